// Round 10
// baseline (113.540 us; speedup 1.0000x reference)
//
#include <hip/hip_runtime.h>

#define EPS 1e-5f
#define LOGITS_N (768 * 768)
#define LOG2E 1.4426950408889634f
#define LN2   0.6931471805599453f

typedef float v2f __attribute__((ext_vector_type(2)));
typedef float v4f __attribute__((ext_vector_type(4)));

// Packed fp32 ops (VOP3P) via inline asm.
__device__ __forceinline__ v2f pk_add(v2f a, v2f b) {
    v2f d; asm("v_pk_add_f32 %0, %1, %2" : "=v"(d) : "v"(a), "v"(b)); return d;
}
__device__ __forceinline__ v2f pk_mul(v2f a, v2f b) {
    v2f d; asm("v_pk_mul_f32 %0, %1, %2" : "=v"(d) : "v"(a), "v"(b)); return d;
}
__device__ __forceinline__ v2f pk_fma(v2f a, v2f b, v2f c) {
    v2f d; asm("v_pk_fma_f32 %0, %1, %2, %3" : "=v"(d) : "v"(a), "v"(b), "v"(c)); return d;
}
#define LO2(v) __builtin_shufflevector(v, v, 0, 1)
#define HI2(v) __builtin_shufflevector(v, v, 2, 3)

// mish(z) = z * tanh(softplus(z)); with t = e^z: mish = z*u/(u+2), u = t(t+2)
__device__ __forceinline__ float mishf(float z) {
    float t = __expf(fminf(z, 40.f));
    float u = t * (t + 2.f);
    return z * u * __builtin_amdgcn_rcpf(u + 2.f);
}

// block of 256 threads (4 waves); returns full sum to all threads
__device__ __forceinline__ float block_sum(float v, float* red) {
#pragma unroll
    for (int off = 32; off > 0; off >>= 1) v += __shfl_down(v, off, 64);
    const int lane = threadIdx.x & 63, wid = threadIdx.x >> 6;
    __syncthreads();
    if (lane == 0) red[wid] = v;
    __syncthreads();
    return red[0] + red[1] + red[2] + red[3];
}

// 2 rows per block (384 blocks). Coalesced float4 weight loads via k-split.
// Outputs CENTERED rows: fi = vi - mean(vi), fjb = (vj+bc1) - mean(vj+bc1),
// plus per-row D' = dot(centered, gc.*wc2). k3's pair variance is then just
// mean((fic+fjc)^2) -- computed in k3's pass 1 with no cross term at all.
__global__ __launch_bounds__(256) void k1_rows(
    const float* __restrict__ h, const float* __restrict__ W0,
    const float* __restrict__ b0, const float* __restrict__ g0,
    const float* __restrict__ be0, const float* __restrict__ W1,
    const float* __restrict__ b1, const float* __restrict__ Wc1,
    const float* __restrict__ bc1, const float* __restrict__ gc,
    const float* __restrict__ bec, const float* __restrict__ wc2,
    float* __restrict__ fi, float* __restrict__ fjb,
    float* __restrict__ stats, float* __restrict__ Gp,
    float* __restrict__ Ep, float* __restrict__ Wp,
    float* __restrict__ consts) {
    __shared__ float shi[256][2];
    __shared__ float sai[256][2];
    __shared__ float sHi[128][2];
    __shared__ float red[4];
    __shared__ float part[4][64][12];
    const int t = threadIdx.x;
    const int i0 = blockIdx.x * 2;
    const float u = gc[t] * wc2[t];
    if (blockIdx.x == 0) {
        Gp[t] = gc[t] * LOG2E;
        Ep[t] = bec[t] * LOG2E;
        Wp[t] = wc2[t] * LN2;
        float sew = block_sum(bec[t] * wc2[t], red);
        if (t == 0) { consts[0] = sew; }
    }
    shi[t][0] = h[i0 * 256 + t];
    shi[t][1] = h[i0 * 256 + 256 + t];
    __syncthreads();
    // ---- GEMM1: x[2][256] = h2 @ W0   (k-split 4 x 64, cols 4/thread) ----
    {
        const int kc = t >> 6, jg = t & 63;
        const float* w0p = W0 + (kc * 64) * 256 + jg * 4;
        float ax[2][4] = {};
#pragma unroll 8
        for (int kk = 0; kk < 64; ++kk) {
            float4 w = *(const float4*)(w0p + kk * 256);
            float2 hh = *(const float2*)&shi[kc * 64 + kk][0];
            ax[0][0] = fmaf(hh.x, w.x, ax[0][0]);
            ax[0][1] = fmaf(hh.x, w.y, ax[0][1]);
            ax[0][2] = fmaf(hh.x, w.z, ax[0][2]);
            ax[0][3] = fmaf(hh.x, w.w, ax[0][3]);
            ax[1][0] = fmaf(hh.y, w.x, ax[1][0]);
            ax[1][1] = fmaf(hh.y, w.y, ax[1][1]);
            ax[1][2] = fmaf(hh.y, w.z, ax[1][2]);
            ax[1][3] = fmaf(hh.y, w.w, ax[1][3]);
        }
        float* pp = &part[kc][jg][0];
#pragma unroll
        for (int c = 0; c < 4; ++c) { pp[c * 2] = ax[0][c]; pp[c * 2 + 1] = ax[1][c]; }
    }
    __syncthreads();
    float x0, x1;
    {
        const int m = t >> 2, c = t & 3;
        x0 = b0[t]; x1 = x0;
#pragma unroll
        for (int kc = 0; kc < 4; ++kc) {
            x0 += part[kc][m][c * 2 + 0];
            x1 += part[kc][m][c * 2 + 1];
        }
    }
    // ---- LN + mish per row ----
    {
        float s1 = block_sum(x0, red), s2 = block_sum(x0 * x0, red);
        float mean = s1 * (1.f / 256.f);
        float var = fmaxf(s2 * (1.f / 256.f) - mean * mean, 0.f);
        float rs = __builtin_amdgcn_rsqf(var + EPS);
        sai[t][0] = mishf((x0 - mean) * rs * g0[t] + be0[t]);
        s1 = block_sum(x1, red); s2 = block_sum(x1 * x1, red);
        mean = s1 * (1.f / 256.f);
        var = fmaxf(s2 * (1.f / 256.f) - mean * mean, 0.f);
        rs = __builtin_amdgcn_rsqf(var + EPS);
        sai[t][1] = mishf((x1 - mean) * rs * g0[t] + be0[t]);
    }
    __syncthreads();
    // ---- GEMM2: H[2][128] = a2 @ W1   (k-split 8 x 32, cols 4/thread) ----
    {
        const int kc = t >> 5, jg = t & 31;
        const float* w1p = W1 + (kc * 32) * 128 + jg * 4;
        float ah[2][4] = {};
#pragma unroll 8
        for (int kk = 0; kk < 32; ++kk) {
            float4 w = *(const float4*)(w1p + kk * 128);
            float2 ss = *(const float2*)&sai[kc * 32 + kk][0];
            ah[0][0] = fmaf(ss.x, w.x, ah[0][0]);
            ah[0][1] = fmaf(ss.x, w.y, ah[0][1]);
            ah[0][2] = fmaf(ss.x, w.z, ah[0][2]);
            ah[0][3] = fmaf(ss.x, w.w, ah[0][3]);
            ah[1][0] = fmaf(ss.y, w.x, ah[1][0]);
            ah[1][1] = fmaf(ss.y, w.y, ah[1][1]);
            ah[1][2] = fmaf(ss.y, w.z, ah[1][2]);
            ah[1][3] = fmaf(ss.y, w.w, ah[1][3]);
        }
        float* pp = &part[0][0][0] + (kc * 32 + jg) * 12;
#pragma unroll
        for (int c = 0; c < 4; ++c) { pp[c * 2] = ah[0][c]; pp[c * 2 + 1] = ah[1][c]; }
    }
    __syncthreads();
    {
        const int r = t >> 7, jj = t & 127;
        float hv = b1[jj];
        const float* pf = &part[0][0][0];
#pragma unroll
        for (int kc = 0; kc < 8; ++kc)
            hv += pf[(kc * 32 + (jj >> 2)) * 12 + (jj & 3) * 2 + r];
        sHi[jj][r] = hv;
    }
    __syncthreads();
    // ---- GEMM3: vi = H@Wi, vj = H@Wj (K=128, k-split 4 x 32) ----
    float avi[2][4] = {}, avj[2][4] = {};
    {
        const int kc = t >> 6, jg = t & 63;
        const float* wip = Wc1 + (kc * 32) * 256 + jg * 4;
        const float* wjp = Wc1 + (128 + kc * 32) * 256 + jg * 4;
#pragma unroll 4
        for (int kk = 0; kk < 32; ++kk) {
            float4 wa = *(const float4*)(wip + kk * 256);
            float4 wb = *(const float4*)(wjp + kk * 256);
            float2 hh = *(const float2*)&sHi[kc * 32 + kk][0];
            avi[0][0] = fmaf(hh.x, wa.x, avi[0][0]);
            avi[0][1] = fmaf(hh.x, wa.y, avi[0][1]);
            avi[0][2] = fmaf(hh.x, wa.z, avi[0][2]);
            avi[0][3] = fmaf(hh.x, wa.w, avi[0][3]);
            avi[1][0] = fmaf(hh.y, wa.x, avi[1][0]);
            avi[1][1] = fmaf(hh.y, wa.y, avi[1][1]);
            avi[1][2] = fmaf(hh.y, wa.z, avi[1][2]);
            avi[1][3] = fmaf(hh.y, wa.w, avi[1][3]);
            avj[0][0] = fmaf(hh.x, wb.x, avj[0][0]);
            avj[0][1] = fmaf(hh.x, wb.y, avj[0][1]);
            avj[0][2] = fmaf(hh.x, wb.z, avj[0][2]);
            avj[0][3] = fmaf(hh.x, wb.w, avj[0][3]);
            avj[1][0] = fmaf(hh.y, wb.x, avj[1][0]);
            avj[1][1] = fmaf(hh.y, wb.y, avj[1][1]);
            avj[1][2] = fmaf(hh.y, wb.z, avj[1][2]);
            avj[1][3] = fmaf(hh.y, wb.w, avj[1][3]);
        }
        float* pp = &part[kc][jg][0];
#pragma unroll
        for (int c = 0; c < 4; ++c) { pp[c * 2] = avi[0][c]; pp[c * 2 + 1] = avi[1][c]; }
    }
    __syncthreads();
    float vi0 = 0.f, vi1 = 0.f;
    {
        const int m = t >> 2, c = t & 3;
#pragma unroll
        for (int kc = 0; kc < 4; ++kc) {
            vi0 += part[kc][m][c * 2 + 0];
            vi1 += part[kc][m][c * 2 + 1];
        }
    }
    __syncthreads();
    {
        const int kc = t >> 6, jg = t & 63;
        float* pp = &part[kc][jg][0];
#pragma unroll
        for (int c = 0; c < 4; ++c) { pp[c * 2] = avj[0][c]; pp[c * 2 + 1] = avj[1][c]; }
    }
    __syncthreads();
    float vj0, vj1;
    {
        const int m = t >> 2, c = t & 3;
        vj0 = bc1[t]; vj1 = vj0;
#pragma unroll
        for (int kc = 0; kc < 4; ++kc) {
            vj0 += part[kc][m][c * 2 + 0];
            vj1 += part[kc][m][c * 2 + 1];
        }
    }
    // ---- Center rows, write centered arrays + per-row D' stats ----
    {
        float su = block_sum(vi0, red);
        float fc = vi0 - su * (1.f / 256.f);
        fi[i0 * 256 + t] = fc;
        float d = block_sum(fc * u, red);
        float sv = block_sum(vj0, red);
        float gcj = vj0 - sv * (1.f / 256.f);
        fjb[i0 * 256 + t] = gcj;
        float dj = block_sum(gcj * u, red);
        if (t == 0) {
            stats[i0 * 8 + 1] = d;
            stats[i0 * 8 + 3] = dj;
        }
        su = block_sum(vi1, red);
        fc = vi1 - su * (1.f / 256.f);
        fi[(i0 + 1) * 256 + t] = fc;
        d = block_sum(fc * u, red);
        sv = block_sum(vj1, red);
        gcj = vj1 - sv * (1.f / 256.f);
        fjb[(i0 + 1) * 256 + t] = gcj;
        dj = block_sum(gcj * u, red);
        if (t == 0) {
            stats[(i0 + 1) * 8 + 1] = d;
            stats[(i0 + 1) * 8 + 3] = dj;
        }
    }
}

// 8-elem packed mish+dot body; xc = fic+fjc is already centered, so
// y = (xc*rs)*G' + E'. One rcp per 8 elems (v >= 2 always; overflow would
// need sum of positive z > 44 across 8 LN'd elems -- impossible).
// Reads xiA/xiB, gA..wB, two2 from enclosing scope; xj from LDS ptr XJP.
#define MISH8(XJP, RS2, ACC0, ACC1)                                          \
    do {                                                                      \
        v4f xjA = *(const v4f*)(XJP);                                         \
        v4f xjB = *(const v4f*)((XJP) + 4);                                   \
        v2f xs0 = pk_add(LO2(xiA), LO2(xjA));                                 \
        v2f xs1 = pk_add(HI2(xiA), HI2(xjA));                                 \
        v2f xs2 = pk_add(LO2(xiB), LO2(xjB));                                 \
        v2f xs3 = pk_add(HI2(xiB), HI2(xjB));                                 \
        v2f y0 = pk_fma(pk_mul(xs0, RS2), LO2(gA), LO2(eA));                  \
        v2f y1 = pk_fma(pk_mul(xs1, RS2), HI2(gA), HI2(eA));                  \
        v2f y2 = pk_fma(pk_mul(xs2, RS2), LO2(gB), LO2(eB));                  \
        v2f y3 = pk_fma(pk_mul(xs3, RS2), HI2(gB), HI2(eB));                  \
        v2f t0, t1, t2, t3;                                                   \
        t0.x = __builtin_amdgcn_exp2f(y0.x); t0.y = __builtin_amdgcn_exp2f(y0.y); \
        t1.x = __builtin_amdgcn_exp2f(y1.x); t1.y = __builtin_amdgcn_exp2f(y1.y); \
        t2.x = __builtin_amdgcn_exp2f(y2.x); t2.y = __builtin_amdgcn_exp2f(y2.y); \
        t3.x = __builtin_amdgcn_exp2f(y3.x); t3.y = __builtin_amdgcn_exp2f(y3.y); \
        v2f v0 = pk_fma(t0, pk_add(t0, two2), two2);                          \
        v2f v1 = pk_fma(t1, pk_add(t1, two2), two2);                          \
        v2f v2_ = pk_fma(t2, pk_add(t2, two2), two2);                         \
        v2f v3 = pk_fma(t3, pk_add(t3, two2), two2);                          \
        v2f Pab = pk_mul(v0, v1), Pcd = pk_mul(v2_, v3);                      \
        v2f Q = pk_mul(Pab, Pcd);                                             \
        float rall = __builtin_amdgcn_rcpf(Q.x * Q.y);                        \
        v2f R1; R1.x = rall * Q.y; R1.y = rall * Q.x;                         \
        v2f Rab = pk_mul(R1, Pcd), Rcd = pk_mul(R1, Pab);                     \
        v2f iv0 = pk_mul(Rab, v1);                                            \
        v2f iv1 = pk_mul(Rab, v0);                                            \
        v2f iv2 = pk_mul(Rcd, v3);                                            \
        v2f iv3 = pk_mul(Rcd, v2_);                                           \
        ACC0 = pk_fma(pk_mul(y0, iv0), LO2(wA), ACC0);                        \
        ACC1 = pk_fma(pk_mul(y1, iv1), HI2(wA), ACC1);                        \
        ACC0 = pk_fma(pk_mul(y2, iv2), LO2(wB), ACC0);                        \
        ACC1 = pk_fma(pk_mul(y3, iv3), HI2(wB), ACC1);                        \
    } while (0)

// R8's proven 16x16 tile / 1 pair/thread, but LDS holds ONLY FJ (16.6 KB ->
// 7-8 resident blocks/CU instead of 4; kills the 9-blocks-per-CU tail).
// xi rows read from global (4 L1-hit lines/wave, fi tile L1-resident);
// G/E/W read from global with an opaque-zero VGPR added to the pointer so
// the compiler emits VECTOR loads (uniform addr -> L1 broadcast), never
// s_load (scalar-cache path deliberately avoided). Arithmetic identical
// to R8: var = mean((fic+fjc)^2), logits = rs*(Di+Dj)+Sew - 2*nl + bc2.
__global__ __launch_bounds__(256, 4) void k3_pair(
    const float* __restrict__ fi, const float* __restrict__ fjb,
    const float* __restrict__ stats,
    const float* __restrict__ Gp, const float* __restrict__ Ep,
    const float* __restrict__ Wp, const float* __restrict__ consts,
    const float* __restrict__ bc2, float* __restrict__ out, int write_mask) {
    __shared__ __align__(16) float FJ[16][260];  // 2-way banks on reads (free)
    const int tid = threadIdx.x;
    const int i0 = blockIdx.y * 16, j0 = blockIdx.x * 16;
#pragma unroll
    for (int l = 0; l < 4; ++l) {    // FJ: 16 rows = 1024 quads
        int idx = tid + l * 256;
        int r = idx >> 6, c = (idx & 63) * 4;
        *(float4*)&FJ[r][c] = *(const float4*)&fjb[(j0 + r) * 256 + c];
    }
    const int ti = tid >> 4, tj = tid & 15;
    const int i = i0 + ti, j = j0 + tj;
    const float Di = stats[i * 8 + 1];
    const float Dj = stats[j * 8 + 3];
    const float Sew = consts[0], bc2f = bc2[0];
    // opaque zero in a VGPR: forces vector loads on wave-uniform addresses
    int zero = 0;
    asm volatile("" : "+v"(zero));
    const v4f* __restrict__ fip = (const v4f*)(fi + i * 256);  // L1-resident
    const v4f* __restrict__ G4 = (const v4f*)(Gp + zero);
    const v4f* __restrict__ E4 = (const v4f*)(Ep + zero);
    const v4f* __restrict__ W4 = (const v4f*)(Wp + zero);
    __syncthreads();
    const float* FJp = &FJ[tj][0];
    // pass 1: var = mean((fic+fjc)^2)  (sum of squares -> no cancellation)
    v2f sqa = {0.f, 0.f}, sqb = {0.f, 0.f};
#pragma unroll 8
    for (int d8 = 0; d8 < 32; ++d8) {
        v4f xiA = fip[d8 * 2];
        v4f xiB = fip[d8 * 2 + 1];
        v4f xjA = *(const v4f*)(FJp + d8 * 8);
        v4f xjB = *(const v4f*)(FJp + d8 * 8 + 4);
        v2f s0 = pk_add(LO2(xiA), LO2(xjA));
        v2f s1 = pk_add(HI2(xiA), HI2(xjA));
        v2f s2 = pk_add(LO2(xiB), LO2(xjB));
        v2f s3 = pk_add(HI2(xiB), HI2(xjB));
        sqa = pk_fma(s0, s0, sqa);
        sqb = pk_fma(s1, s1, sqb);
        sqa = pk_fma(s2, s2, sqa);
        sqb = pk_fma(s3, s3, sqb);
    }
    const float var = ((sqa.x + sqa.y) + (sqb.x + sqb.y)) * (1.f / 256.f);
    const float rs = __builtin_amdgcn_rsqf(var + EPS);
    const float lin = fmaf(rs, Di + Dj, Sew);
    // pass 2: nonlinear term
    const v2f rs2 = {rs, rs};
    const v2f two2 = {2.f, 2.f};
    v2f acc0 = {0.f, 0.f}, acc1 = {0.f, 0.f};
#pragma unroll 2
    for (int d8 = 0; d8 < 32; ++d8) {
        v4f xiA = fip[d8 * 2];
        v4f xiB = fip[d8 * 2 + 1];
        v4f gA = G4[d8 * 2], gB = G4[d8 * 2 + 1];
        v4f eA = E4[d8 * 2], eB = E4[d8 * 2 + 1];
        v4f wA = W4[d8 * 2], wB = W4[d8 * 2 + 1];
        MISH8(FJp + d8 * 8, rs2, acc0, acc1);
    }
    const float nl = (acc0.x + acc0.y) + (acc1.x + acc1.y);
    out[i * 768 + j] = fmaf(-2.f, nl, lin) + bc2f;
    if (write_mask) out[LOGITS_N + i * 768 + j] = 1.0f;
}

extern "C" void kernel_launch(void* const* d_in, const int* in_sizes, int n_in,
                              void* d_out, int out_size, void* d_ws, size_t ws_size,
                              hipStream_t stream) {
    const float* h   = (const float*)d_in[0];
    const float* W0  = (const float*)d_in[1];
    const float* b0  = (const float*)d_in[2];
    const float* g0  = (const float*)d_in[3];
    const float* be0 = (const float*)d_in[4];
    const float* W1  = (const float*)d_in[5];
    const float* b1  = (const float*)d_in[6];
    const float* Wc1 = (const float*)d_in[7];
    const float* bc1 = (const float*)d_in[8];
    const float* gc  = (const float*)d_in[9];
    const float* bec = (const float*)d_in[10];
    const float* Wc2 = (const float*)d_in[11];
    const float* bc2 = (const float*)d_in[12];
    float* ws = (float*)d_ws;
    float* fi     = ws;             // 768*256
    float* fjb    = ws + 196608;    // 768*256
    float* stats  = ws + 393216;    // 768*8
    float* Gp     = ws + 399360;    // 256
    float* Ep     = ws + 399616;    // 256
    float* Wp     = ws + 399872;    // 256
    float* consts = ws + 400128;    // 4
    float* out = (float*)d_out;
    int write_mask = (out_size >= 2 * LOGITS_N) ? 1 : 0;

    k1_rows<<<dim3(384), dim3(256), 0, stream>>>(h, W0, b0, g0, be0, W1, b1,
                                                 Wc1, bc1, gc, bec, Wc2,
                                                 fi, fjb, stats, Gp, Ep, Wp,
                                                 consts);
    k3_pair<<<dim3(48, 48), dim3(256), 0, stream>>>(fi, fjb, stats,
                                                    Gp, Ep, Wp, consts, bc2,
                                                    out, write_mask);
}

// Round 11
// 76.473 us; speedup vs baseline: 1.4847x; 1.4847x over previous
//
#include <hip/hip_runtime.h>

#define EPS 1e-5f
#define LOGITS_N (768 * 768)
#define LOG2E 1.4426950408889634f
#define LN2   0.6931471805599453f

typedef float v2f __attribute__((ext_vector_type(2)));
typedef float v4f __attribute__((ext_vector_type(4)));

// Packed fp32 ops (VOP3P) via inline asm.
__device__ __forceinline__ v2f pk_add(v2f a, v2f b) {
    v2f d; asm("v_pk_add_f32 %0, %1, %2" : "=v"(d) : "v"(a), "v"(b)); return d;
}
__device__ __forceinline__ v2f pk_mul(v2f a, v2f b) {
    v2f d; asm("v_pk_mul_f32 %0, %1, %2" : "=v"(d) : "v"(a), "v"(b)); return d;
}
__device__ __forceinline__ v2f pk_fma(v2f a, v2f b, v2f c) {
    v2f d; asm("v_pk_fma_f32 %0, %1, %2, %3" : "=v"(d) : "v"(a), "v"(b), "v"(c)); return d;
}
#define LO2(v) __builtin_shufflevector(v, v, 0, 1)
#define HI2(v) __builtin_shufflevector(v, v, 2, 3)

// mish(z) = z * tanh(softplus(z)); with t = e^z: mish = z*u/(u+2), u = t(t+2)
__device__ __forceinline__ float mishf(float z) {
    float t = __expf(fminf(z, 40.f));
    float u = t * (t + 2.f);
    return z * u * __builtin_amdgcn_rcpf(u + 2.f);
}

// block of 256 threads (4 waves); returns full sum to all threads
__device__ __forceinline__ float block_sum(float v, float* red) {
#pragma unroll
    for (int off = 32; off > 0; off >>= 1) v += __shfl_down(v, off, 64);
    const int lane = threadIdx.x & 63, wid = threadIdx.x >> 6;
    __syncthreads();
    if (lane == 0) red[wid] = v;
    __syncthreads();
    return red[0] + red[1] + red[2] + red[3];
}

// 2 rows per block (384 blocks). Coalesced float4 weight loads via k-split.
// Outputs CENTERED rows: fi = vi - mean(vi), fjb = (vj+bc1) - mean(vj+bc1),
// plus per-row D' = dot(centered, gc.*wc2). k3's pair variance is then just
// mean((fic+fjc)^2) -- computed in k3's pass 1 with no cross term at all.
__global__ __launch_bounds__(256) void k1_rows(
    const float* __restrict__ h, const float* __restrict__ W0,
    const float* __restrict__ b0, const float* __restrict__ g0,
    const float* __restrict__ be0, const float* __restrict__ W1,
    const float* __restrict__ b1, const float* __restrict__ Wc1,
    const float* __restrict__ bc1, const float* __restrict__ gc,
    const float* __restrict__ bec, const float* __restrict__ wc2,
    float* __restrict__ fi, float* __restrict__ fjb,
    float* __restrict__ stats, float* __restrict__ Gp,
    float* __restrict__ Ep, float* __restrict__ Wp,
    float* __restrict__ consts) {
    __shared__ float shi[256][2];
    __shared__ float sai[256][2];
    __shared__ float sHi[128][2];
    __shared__ float red[4];
    __shared__ float part[4][64][12];
    const int t = threadIdx.x;
    const int i0 = blockIdx.x * 2;
    const float u = gc[t] * wc2[t];
    if (blockIdx.x == 0) {
        Gp[t] = gc[t] * LOG2E;
        Ep[t] = bec[t] * LOG2E;
        Wp[t] = wc2[t] * LN2;
        float sew = block_sum(bec[t] * wc2[t], red);
        if (t == 0) { consts[0] = sew; }
    }
    shi[t][0] = h[i0 * 256 + t];
    shi[t][1] = h[i0 * 256 + 256 + t];
    __syncthreads();
    // ---- GEMM1: x[2][256] = h2 @ W0   (k-split 4 x 64, cols 4/thread) ----
    {
        const int kc = t >> 6, jg = t & 63;
        const float* w0p = W0 + (kc * 64) * 256 + jg * 4;
        float ax[2][4] = {};
#pragma unroll 8
        for (int kk = 0; kk < 64; ++kk) {
            float4 w = *(const float4*)(w0p + kk * 256);
            float2 hh = *(const float2*)&shi[kc * 64 + kk][0];
            ax[0][0] = fmaf(hh.x, w.x, ax[0][0]);
            ax[0][1] = fmaf(hh.x, w.y, ax[0][1]);
            ax[0][2] = fmaf(hh.x, w.z, ax[0][2]);
            ax[0][3] = fmaf(hh.x, w.w, ax[0][3]);
            ax[1][0] = fmaf(hh.y, w.x, ax[1][0]);
            ax[1][1] = fmaf(hh.y, w.y, ax[1][1]);
            ax[1][2] = fmaf(hh.y, w.z, ax[1][2]);
            ax[1][3] = fmaf(hh.y, w.w, ax[1][3]);
        }
        float* pp = &part[kc][jg][0];
#pragma unroll
        for (int c = 0; c < 4; ++c) { pp[c * 2] = ax[0][c]; pp[c * 2 + 1] = ax[1][c]; }
    }
    __syncthreads();
    float x0, x1;
    {
        const int m = t >> 2, c = t & 3;
        x0 = b0[t]; x1 = x0;
#pragma unroll
        for (int kc = 0; kc < 4; ++kc) {
            x0 += part[kc][m][c * 2 + 0];
            x1 += part[kc][m][c * 2 + 1];
        }
    }
    // ---- LN + mish per row ----
    {
        float s1 = block_sum(x0, red), s2 = block_sum(x0 * x0, red);
        float mean = s1 * (1.f / 256.f);
        float var = fmaxf(s2 * (1.f / 256.f) - mean * mean, 0.f);
        float rs = __builtin_amdgcn_rsqf(var + EPS);
        sai[t][0] = mishf((x0 - mean) * rs * g0[t] + be0[t]);
        s1 = block_sum(x1, red); s2 = block_sum(x1 * x1, red);
        mean = s1 * (1.f / 256.f);
        var = fmaxf(s2 * (1.f / 256.f) - mean * mean, 0.f);
        rs = __builtin_amdgcn_rsqf(var + EPS);
        sai[t][1] = mishf((x1 - mean) * rs * g0[t] + be0[t]);
    }
    __syncthreads();
    // ---- GEMM2: H[2][128] = a2 @ W1   (k-split 8 x 32, cols 4/thread) ----
    {
        const int kc = t >> 5, jg = t & 31;
        const float* w1p = W1 + (kc * 32) * 128 + jg * 4;
        float ah[2][4] = {};
#pragma unroll 8
        for (int kk = 0; kk < 32; ++kk) {
            float4 w = *(const float4*)(w1p + kk * 128);
            float2 ss = *(const float2*)&sai[kc * 32 + kk][0];
            ah[0][0] = fmaf(ss.x, w.x, ah[0][0]);
            ah[0][1] = fmaf(ss.x, w.y, ah[0][1]);
            ah[0][2] = fmaf(ss.x, w.z, ah[0][2]);
            ah[0][3] = fmaf(ss.x, w.w, ah[0][3]);
            ah[1][0] = fmaf(ss.y, w.x, ah[1][0]);
            ah[1][1] = fmaf(ss.y, w.y, ah[1][1]);
            ah[1][2] = fmaf(ss.y, w.z, ah[1][2]);
            ah[1][3] = fmaf(ss.y, w.w, ah[1][3]);
        }
        float* pp = &part[0][0][0] + (kc * 32 + jg) * 12;
#pragma unroll
        for (int c = 0; c < 4; ++c) { pp[c * 2] = ah[0][c]; pp[c * 2 + 1] = ah[1][c]; }
    }
    __syncthreads();
    {
        const int r = t >> 7, jj = t & 127;
        float hv = b1[jj];
        const float* pf = &part[0][0][0];
#pragma unroll
        for (int kc = 0; kc < 8; ++kc)
            hv += pf[(kc * 32 + (jj >> 2)) * 12 + (jj & 3) * 2 + r];
        sHi[jj][r] = hv;
    }
    __syncthreads();
    // ---- GEMM3: vi = H@Wi, vj = H@Wj (K=128, k-split 4 x 32) ----
    float avi[2][4] = {}, avj[2][4] = {};
    {
        const int kc = t >> 6, jg = t & 63;
        const float* wip = Wc1 + (kc * 32) * 256 + jg * 4;
        const float* wjp = Wc1 + (128 + kc * 32) * 256 + jg * 4;
#pragma unroll 4
        for (int kk = 0; kk < 32; ++kk) {
            float4 wa = *(const float4*)(wip + kk * 256);
            float4 wb = *(const float4*)(wjp + kk * 256);
            float2 hh = *(const float2*)&sHi[kc * 32 + kk][0];
            avi[0][0] = fmaf(hh.x, wa.x, avi[0][0]);
            avi[0][1] = fmaf(hh.x, wa.y, avi[0][1]);
            avi[0][2] = fmaf(hh.x, wa.z, avi[0][2]);
            avi[0][3] = fmaf(hh.x, wa.w, avi[0][3]);
            avi[1][0] = fmaf(hh.y, wa.x, avi[1][0]);
            avi[1][1] = fmaf(hh.y, wa.y, avi[1][1]);
            avi[1][2] = fmaf(hh.y, wa.z, avi[1][2]);
            avi[1][3] = fmaf(hh.y, wa.w, avi[1][3]);
            avj[0][0] = fmaf(hh.x, wb.x, avj[0][0]);
            avj[0][1] = fmaf(hh.x, wb.y, avj[0][1]);
            avj[0][2] = fmaf(hh.x, wb.z, avj[0][2]);
            avj[0][3] = fmaf(hh.x, wb.w, avj[0][3]);
            avj[1][0] = fmaf(hh.y, wb.x, avj[1][0]);
            avj[1][1] = fmaf(hh.y, wb.y, avj[1][1]);
            avj[1][2] = fmaf(hh.y, wb.z, avj[1][2]);
            avj[1][3] = fmaf(hh.y, wb.w, avj[1][3]);
        }
        float* pp = &part[kc][jg][0];
#pragma unroll
        for (int c = 0; c < 4; ++c) { pp[c * 2] = avi[0][c]; pp[c * 2 + 1] = avi[1][c]; }
    }
    __syncthreads();
    float vi0 = 0.f, vi1 = 0.f;
    {
        const int m = t >> 2, c = t & 3;
#pragma unroll
        for (int kc = 0; kc < 4; ++kc) {
            vi0 += part[kc][m][c * 2 + 0];
            vi1 += part[kc][m][c * 2 + 1];
        }
    }
    __syncthreads();
    {
        const int kc = t >> 6, jg = t & 63;
        float* pp = &part[kc][jg][0];
#pragma unroll
        for (int c = 0; c < 4; ++c) { pp[c * 2] = avj[0][c]; pp[c * 2 + 1] = avj[1][c]; }
    }
    __syncthreads();
    float vj0, vj1;
    {
        const int m = t >> 2, c = t & 3;
        vj0 = bc1[t]; vj1 = vj0;
#pragma unroll
        for (int kc = 0; kc < 4; ++kc) {
            vj0 += part[kc][m][c * 2 + 0];
            vj1 += part[kc][m][c * 2 + 1];
        }
    }
    // ---- Center rows, write centered arrays + per-row D' stats ----
    {
        float su = block_sum(vi0, red);
        float fc = vi0 - su * (1.f / 256.f);
        fi[i0 * 256 + t] = fc;
        float d = block_sum(fc * u, red);
        float sv = block_sum(vj0, red);
        float gcj = vj0 - sv * (1.f / 256.f);
        fjb[i0 * 256 + t] = gcj;
        float dj = block_sum(gcj * u, red);
        if (t == 0) {
            stats[i0 * 8 + 1] = d;
            stats[i0 * 8 + 3] = dj;
        }
        su = block_sum(vi1, red);
        fc = vi1 - su * (1.f / 256.f);
        fi[(i0 + 1) * 256 + t] = fc;
        d = block_sum(fc * u, red);
        sv = block_sum(vj1, red);
        gcj = vj1 - sv * (1.f / 256.f);
        fjb[(i0 + 1) * 256 + t] = gcj;
        dj = block_sum(gcj * u, red);
        if (t == 0) {
            stats[(i0 + 1) * 8 + 1] = d;
            stats[(i0 + 1) * 8 + 3] = dj;
        }
    }
}

// 8-elem packed mish+dot body; xc = fic+fjc is already centered, so
// y = (xc*rs)*G' + E'. One rcp per 8 elems (v >= 2 always; overflow would
// need sum of positive z > 44 across 8 LN'd elems -- impossible).
// Reads xiA/xiB, gA..wB, two2 from enclosing scope; xj from LDS ptr XJP.
#define MISH8(XJP, RS2, ACC0, ACC1)                                          \
    do {                                                                      \
        v4f xjA = *(const v4f*)(XJP);                                         \
        v4f xjB = *(const v4f*)((XJP) + 4);                                   \
        v2f xs0 = pk_add(LO2(xiA), LO2(xjA));                                 \
        v2f xs1 = pk_add(HI2(xiA), HI2(xjA));                                 \
        v2f xs2 = pk_add(LO2(xiB), LO2(xjB));                                 \
        v2f xs3 = pk_add(HI2(xiB), HI2(xjB));                                 \
        v2f y0 = pk_fma(pk_mul(xs0, RS2), LO2(gA), LO2(eA));                  \
        v2f y1 = pk_fma(pk_mul(xs1, RS2), HI2(gA), HI2(eA));                  \
        v2f y2 = pk_fma(pk_mul(xs2, RS2), LO2(gB), LO2(eB));                  \
        v2f y3 = pk_fma(pk_mul(xs3, RS2), HI2(gB), HI2(eB));                  \
        v2f t0, t1, t2, t3;                                                   \
        t0.x = __builtin_amdgcn_exp2f(y0.x); t0.y = __builtin_amdgcn_exp2f(y0.y); \
        t1.x = __builtin_amdgcn_exp2f(y1.x); t1.y = __builtin_amdgcn_exp2f(y1.y); \
        t2.x = __builtin_amdgcn_exp2f(y2.x); t2.y = __builtin_amdgcn_exp2f(y2.y); \
        t3.x = __builtin_amdgcn_exp2f(y3.x); t3.y = __builtin_amdgcn_exp2f(y3.y); \
        v2f v0 = pk_fma(t0, pk_add(t0, two2), two2);                          \
        v2f v1 = pk_fma(t1, pk_add(t1, two2), two2);                          \
        v2f v2_ = pk_fma(t2, pk_add(t2, two2), two2);                         \
        v2f v3 = pk_fma(t3, pk_add(t3, two2), two2);                          \
        v2f Pab = pk_mul(v0, v1), Pcd = pk_mul(v2_, v3);                      \
        v2f Q = pk_mul(Pab, Pcd);                                             \
        float rall = __builtin_amdgcn_rcpf(Q.x * Q.y);                        \
        v2f R1; R1.x = rall * Q.y; R1.y = rall * Q.x;                         \
        v2f Rab = pk_mul(R1, Pcd), Rcd = pk_mul(R1, Pab);                     \
        v2f iv0 = pk_mul(Rab, v1);                                            \
        v2f iv1 = pk_mul(Rab, v0);                                            \
        v2f iv2 = pk_mul(Rcd, v3);                                            \
        v2f iv3 = pk_mul(Rcd, v2_);                                           \
        ACC0 = pk_fma(pk_mul(y0, iv0), LO2(wA), ACC0);                        \
        ACC1 = pk_fma(pk_mul(y1, iv1), HI2(wA), ACC1);                        \
        ACC0 = pk_fma(pk_mul(y2, iv2), LO2(wB), ACC0);                        \
        ACC1 = pk_fma(pk_mul(y3, iv3), HI2(wB), ACC1);                        \
    } while (0)

// R8's proven 16x16 tile / 1 pair/thread. HYBRID operand placement:
// FJ + G/E/W in LDS (cheap broadcast reads, proven paths, 19.7 KB ->
// 8 blocks/CU); ONLY xi from global (2 coalesced loads/d8, 4 L1 lines/wave,
// L1/L2-resident) -- R10's mistake was ALSO putting G/E/W on the VMEM pipe.
// Arithmetic identical to R8: var = mean((fic+fjc)^2) (no cancellation),
// logits = rs*(Di+Dj)+Sew - 2*nl + bc2.
__global__ __launch_bounds__(256, 8) void k3_pair(
    const float* __restrict__ fi, const float* __restrict__ fjb,
    const float* __restrict__ stats,
    const float* __restrict__ Gp, const float* __restrict__ Ep,
    const float* __restrict__ Wp, const float* __restrict__ consts,
    const float* __restrict__ bc2, float* __restrict__ out, int write_mask) {
    __shared__ __align__(16) float FJ[16][260];  // 2-way banks on reads (free)
    __shared__ __align__(16) float Gs[256], Es[256], Ws[256];
    const int tid = threadIdx.x;
    const int i0 = blockIdx.y * 16, j0 = blockIdx.x * 16;
#pragma unroll
    for (int l = 0; l < 4; ++l) {    // FJ: 16 rows = 1024 quads
        int idx = tid + l * 256;
        int r = idx >> 6, c = (idx & 63) * 4;
        *(float4*)&FJ[r][c] = *(const float4*)&fjb[(j0 + r) * 256 + c];
    }
    Gs[tid] = Gp[tid];
    Es[tid] = Ep[tid];
    Ws[tid] = Wp[tid];
    const int ti = tid >> 4, tj = tid & 15;
    const int i = i0 + ti, j = j0 + tj;
    const float Di = stats[i * 8 + 1];
    const float Dj = stats[j * 8 + 3];
    const float Sew = consts[0], bc2f = bc2[0];
    const v4f* __restrict__ fip = (const v4f*)(fi + i * 256);  // L1/L2 resident
    __syncthreads();
    const float* FJp = &FJ[tj][0];
    // pass 1: var = mean((fic+fjc)^2)  (sum of squares -> no cancellation)
    v2f sqa = {0.f, 0.f}, sqb = {0.f, 0.f};
#pragma unroll 8
    for (int d8 = 0; d8 < 32; ++d8) {
        v4f xiA = fip[d8 * 2];
        v4f xiB = fip[d8 * 2 + 1];
        v4f xjA = *(const v4f*)(FJp + d8 * 8);
        v4f xjB = *(const v4f*)(FJp + d8 * 8 + 4);
        v2f s0 = pk_add(LO2(xiA), LO2(xjA));
        v2f s1 = pk_add(HI2(xiA), HI2(xjA));
        v2f s2 = pk_add(LO2(xiB), LO2(xjB));
        v2f s3 = pk_add(HI2(xiB), HI2(xjB));
        sqa = pk_fma(s0, s0, sqa);
        sqb = pk_fma(s1, s1, sqb);
        sqa = pk_fma(s2, s2, sqa);
        sqb = pk_fma(s3, s3, sqb);
    }
    const float var = ((sqa.x + sqa.y) + (sqb.x + sqb.y)) * (1.f / 256.f);
    const float rs = __builtin_amdgcn_rsqf(var + EPS);
    const float lin = fmaf(rs, Di + Dj, Sew);
    // pass 2: nonlinear term; xi from global, xj/G/E/W from LDS
    const v4f* G4 = (const v4f*)&Gs[0];
    const v4f* E4 = (const v4f*)&Es[0];
    const v4f* W4 = (const v4f*)&Ws[0];
    const v2f rs2 = {rs, rs};
    const v2f two2 = {2.f, 2.f};
    v2f acc0 = {0.f, 0.f}, acc1 = {0.f, 0.f};
#pragma unroll 2
    for (int d8 = 0; d8 < 32; ++d8) {
        v4f xiA = fip[d8 * 2];
        v4f xiB = fip[d8 * 2 + 1];
        v4f gA = G4[d8 * 2], gB = G4[d8 * 2 + 1];
        v4f eA = E4[d8 * 2], eB = E4[d8 * 2 + 1];
        v4f wA = W4[d8 * 2], wB = W4[d8 * 2 + 1];
        MISH8(FJp + d8 * 8, rs2, acc0, acc1);
    }
    const float nl = (acc0.x + acc0.y) + (acc1.x + acc1.y);
    out[i * 768 + j] = fmaf(-2.f, nl, lin) + bc2f;
    if (write_mask) out[LOGITS_N + i * 768 + j] = 1.0f;
}

extern "C" void kernel_launch(void* const* d_in, const int* in_sizes, int n_in,
                              void* d_out, int out_size, void* d_ws, size_t ws_size,
                              hipStream_t stream) {
    const float* h   = (const float*)d_in[0];
    const float* W0  = (const float*)d_in[1];
    const float* b0  = (const float*)d_in[2];
    const float* g0  = (const float*)d_in[3];
    const float* be0 = (const float*)d_in[4];
    const float* W1  = (const float*)d_in[5];
    const float* b1  = (const float*)d_in[6];
    const float* Wc1 = (const float*)d_in[7];
    const float* bc1 = (const float*)d_in[8];
    const float* gc  = (const float*)d_in[9];
    const float* bec = (const float*)d_in[10];
    const float* Wc2 = (const float*)d_in[11];
    const float* bc2 = (const float*)d_in[12];
    float* ws = (float*)d_ws;
    float* fi     = ws;             // 768*256
    float* fjb    = ws + 196608;    // 768*256
    float* stats  = ws + 393216;    // 768*8
    float* Gp     = ws + 399360;    // 256
    float* Ep     = ws + 399616;    // 256
    float* Wp     = ws + 399872;    // 256
    float* consts = ws + 400128;    // 4
    float* out = (float*)d_out;
    int write_mask = (out_size >= 2 * LOGITS_N) ? 1 : 0;

    k1_rows<<<dim3(384), dim3(256), 0, stream>>>(h, W0, b0, g0, be0, W1, b1,
                                                 Wc1, bc1, gc, bec, Wc2,
                                                 fi, fjb, stats, Gp, Ep, Wp,
                                                 consts);
    k3_pair<<<dim3(48, 48), dim3(256), 0, stream>>>(fi, fjb, stats,
                                                    Gp, Ep, Wp, consts, bc2,
                                                    out, write_mask);
}

// Round 13
// 72.065 us; speedup vs baseline: 1.5755x; 1.0612x over previous
//
#include <hip/hip_runtime.h>

#define EPS 1e-5f
#define LOGITS_N (768 * 768)
#define LOG2E 1.4426950408889634f
#define LN2   0.6931471805599453f

typedef float v2f __attribute__((ext_vector_type(2)));
typedef float v4f __attribute__((ext_vector_type(4)));

// Packed fp32 ops (VOP3P) via inline asm.
__device__ __forceinline__ v2f pk_add(v2f a, v2f b) {
    v2f d; asm("v_pk_add_f32 %0, %1, %2" : "=v"(d) : "v"(a), "v"(b)); return d;
}
__device__ __forceinline__ v2f pk_mul(v2f a, v2f b) {
    v2f d; asm("v_pk_mul_f32 %0, %1, %2" : "=v"(d) : "v"(a), "v"(b)); return d;
}
__device__ __forceinline__ v2f pk_fma(v2f a, v2f b, v2f c) {
    v2f d; asm("v_pk_fma_f32 %0, %1, %2, %3" : "=v"(d) : "v"(a), "v"(b), "v"(c)); return d;
}
#define LO2(v) __builtin_shufflevector(v, v, 0, 1)
#define HI2(v) __builtin_shufflevector(v, v, 2, 3)

// mish(z) = z * tanh(softplus(z)); with t = e^z: mish = z*u/(u+2), u = t(t+2)
__device__ __forceinline__ float mishf(float z) {
    float t = __expf(fminf(z, 40.f));
    float u = t * (t + 2.f);
    return z * u * __builtin_amdgcn_rcpf(u + 2.f);
}

// block of 256 threads (4 waves); returns full sum to all threads
__device__ __forceinline__ float block_sum(float v, float* red) {
#pragma unroll
    for (int off = 32; off > 0; off >>= 1) v += __shfl_down(v, off, 64);
    const int lane = threadIdx.x & 63, wid = threadIdx.x >> 6;
    __syncthreads();
    if (lane == 0) red[wid] = v;
    __syncthreads();
    return red[0] + red[1] + red[2] + red[3];
}

// 2 rows per block (384 blocks). Coalesced float4 weight loads via k-split.
// Outputs CENTERED rows: fi = vi - mean(vi), fjb = (vj+bc1) - mean(vj+bc1),
// plus per-row D' = dot(centered, gc.*wc2). k3's pair variance is then just
// mean((fic+fjc)^2) -- computed in k3's pass 1 with no cross term at all.
__global__ __launch_bounds__(256) void k1_rows(
    const float* __restrict__ h, const float* __restrict__ W0,
    const float* __restrict__ b0, const float* __restrict__ g0,
    const float* __restrict__ be0, const float* __restrict__ W1,
    const float* __restrict__ b1, const float* __restrict__ Wc1,
    const float* __restrict__ bc1, const float* __restrict__ gc,
    const float* __restrict__ bec, const float* __restrict__ wc2,
    float* __restrict__ fi, float* __restrict__ fjb,
    float* __restrict__ stats, float* __restrict__ Gp,
    float* __restrict__ Ep, float* __restrict__ Wp,
    float* __restrict__ consts) {
    __shared__ float shi[256][2];
    __shared__ float sai[256][2];
    __shared__ float sHi[128][2];
    __shared__ float red[4];
    __shared__ float part[4][64][12];
    const int t = threadIdx.x;
    const int i0 = blockIdx.x * 2;
    const float u = gc[t] * wc2[t];
    if (blockIdx.x == 0) {
        Gp[t] = gc[t] * LOG2E;
        Ep[t] = bec[t] * LOG2E;
        Wp[t] = wc2[t] * LN2;
        float sew = block_sum(bec[t] * wc2[t], red);
        if (t == 0) { consts[0] = sew; }
    }
    shi[t][0] = h[i0 * 256 + t];
    shi[t][1] = h[i0 * 256 + 256 + t];
    __syncthreads();
    // ---- GEMM1: x[2][256] = h2 @ W0   (k-split 4 x 64, cols 4/thread) ----
    {
        const int kc = t >> 6, jg = t & 63;
        const float* w0p = W0 + (kc * 64) * 256 + jg * 4;
        float ax[2][4] = {};
#pragma unroll 8
        for (int kk = 0; kk < 64; ++kk) {
            float4 w = *(const float4*)(w0p + kk * 256);
            float2 hh = *(const float2*)&shi[kc * 64 + kk][0];
            ax[0][0] = fmaf(hh.x, w.x, ax[0][0]);
            ax[0][1] = fmaf(hh.x, w.y, ax[0][1]);
            ax[0][2] = fmaf(hh.x, w.z, ax[0][2]);
            ax[0][3] = fmaf(hh.x, w.w, ax[0][3]);
            ax[1][0] = fmaf(hh.y, w.x, ax[1][0]);
            ax[1][1] = fmaf(hh.y, w.y, ax[1][1]);
            ax[1][2] = fmaf(hh.y, w.z, ax[1][2]);
            ax[1][3] = fmaf(hh.y, w.w, ax[1][3]);
        }
        float* pp = &part[kc][jg][0];
#pragma unroll
        for (int c = 0; c < 4; ++c) { pp[c * 2] = ax[0][c]; pp[c * 2 + 1] = ax[1][c]; }
    }
    __syncthreads();
    float x0, x1;
    {
        const int m = t >> 2, c = t & 3;
        x0 = b0[t]; x1 = x0;
#pragma unroll
        for (int kc = 0; kc < 4; ++kc) {
            x0 += part[kc][m][c * 2 + 0];
            x1 += part[kc][m][c * 2 + 1];
        }
    }
    // ---- LN + mish per row ----
    {
        float s1 = block_sum(x0, red), s2 = block_sum(x0 * x0, red);
        float mean = s1 * (1.f / 256.f);
        float var = fmaxf(s2 * (1.f / 256.f) - mean * mean, 0.f);
        float rs = __builtin_amdgcn_rsqf(var + EPS);
        sai[t][0] = mishf((x0 - mean) * rs * g0[t] + be0[t]);
        s1 = block_sum(x1, red); s2 = block_sum(x1 * x1, red);
        mean = s1 * (1.f / 256.f);
        var = fmaxf(s2 * (1.f / 256.f) - mean * mean, 0.f);
        rs = __builtin_amdgcn_rsqf(var + EPS);
        sai[t][1] = mishf((x1 - mean) * rs * g0[t] + be0[t]);
    }
    __syncthreads();
    // ---- GEMM2: H[2][128] = a2 @ W1   (k-split 8 x 32, cols 4/thread) ----
    {
        const int kc = t >> 5, jg = t & 31;
        const float* w1p = W1 + (kc * 32) * 128 + jg * 4;
        float ah[2][4] = {};
#pragma unroll 8
        for (int kk = 0; kk < 32; ++kk) {
            float4 w = *(const float4*)(w1p + kk * 128);
            float2 ss = *(const float2*)&sai[kc * 32 + kk][0];
            ah[0][0] = fmaf(ss.x, w.x, ah[0][0]);
            ah[0][1] = fmaf(ss.x, w.y, ah[0][1]);
            ah[0][2] = fmaf(ss.x, w.z, ah[0][2]);
            ah[0][3] = fmaf(ss.x, w.w, ah[0][3]);
            ah[1][0] = fmaf(ss.y, w.x, ah[1][0]);
            ah[1][1] = fmaf(ss.y, w.y, ah[1][1]);
            ah[1][2] = fmaf(ss.y, w.z, ah[1][2]);
            ah[1][3] = fmaf(ss.y, w.w, ah[1][3]);
        }
        float* pp = &part[0][0][0] + (kc * 32 + jg) * 12;
#pragma unroll
        for (int c = 0; c < 4; ++c) { pp[c * 2] = ah[0][c]; pp[c * 2 + 1] = ah[1][c]; }
    }
    __syncthreads();
    {
        const int r = t >> 7, jj = t & 127;
        float hv = b1[jj];
        const float* pf = &part[0][0][0];
#pragma unroll
        for (int kc = 0; kc < 8; ++kc)
            hv += pf[(kc * 32 + (jj >> 2)) * 12 + (jj & 3) * 2 + r];
        sHi[jj][r] = hv;
    }
    __syncthreads();
    // ---- GEMM3: vi = H@Wi, vj = H@Wj (K=128, k-split 4 x 32) ----
    float avi[2][4] = {}, avj[2][4] = {};
    {
        const int kc = t >> 6, jg = t & 63;
        const float* wip = Wc1 + (kc * 32) * 256 + jg * 4;
        const float* wjp = Wc1 + (128 + kc * 32) * 256 + jg * 4;
#pragma unroll 4
        for (int kk = 0; kk < 32; ++kk) {
            float4 wa = *(const float4*)(wip + kk * 256);
            float4 wb = *(const float4*)(wjp + kk * 256);
            float2 hh = *(const float2*)&sHi[kc * 32 + kk][0];
            avi[0][0] = fmaf(hh.x, wa.x, avi[0][0]);
            avi[0][1] = fmaf(hh.x, wa.y, avi[0][1]);
            avi[0][2] = fmaf(hh.x, wa.z, avi[0][2]);
            avi[0][3] = fmaf(hh.x, wa.w, avi[0][3]);
            avi[1][0] = fmaf(hh.y, wa.x, avi[1][0]);
            avi[1][1] = fmaf(hh.y, wa.y, avi[1][1]);
            avi[1][2] = fmaf(hh.y, wa.z, avi[1][2]);
            avi[1][3] = fmaf(hh.y, wa.w, avi[1][3]);
            avj[0][0] = fmaf(hh.x, wb.x, avj[0][0]);
            avj[0][1] = fmaf(hh.x, wb.y, avj[0][1]);
            avj[0][2] = fmaf(hh.x, wb.z, avj[0][2]);
            avj[0][3] = fmaf(hh.x, wb.w, avj[0][3]);
            avj[1][0] = fmaf(hh.y, wb.x, avj[1][0]);
            avj[1][1] = fmaf(hh.y, wb.y, avj[1][1]);
            avj[1][2] = fmaf(hh.y, wb.z, avj[1][2]);
            avj[1][3] = fmaf(hh.y, wb.w, avj[1][3]);
        }
        float* pp = &part[kc][jg][0];
#pragma unroll
        for (int c = 0; c < 4; ++c) { pp[c * 2] = avi[0][c]; pp[c * 2 + 1] = avi[1][c]; }
    }
    __syncthreads();
    float vi0 = 0.f, vi1 = 0.f;
    {
        const int m = t >> 2, c = t & 3;
#pragma unroll
        for (int kc = 0; kc < 4; ++kc) {
            vi0 += part[kc][m][c * 2 + 0];
            vi1 += part[kc][m][c * 2 + 1];
        }
    }
    __syncthreads();
    {
        const int kc = t >> 6, jg = t & 63;
        float* pp = &part[kc][jg][0];
#pragma unroll
        for (int c = 0; c < 4; ++c) { pp[c * 2] = avj[0][c]; pp[c * 2 + 1] = avj[1][c]; }
    }
    __syncthreads();
    float vj0, vj1;
    {
        const int m = t >> 2, c = t & 3;
        vj0 = bc1[t]; vj1 = vj0;
#pragma unroll
        for (int kc = 0; kc < 4; ++kc) {
            vj0 += part[kc][m][c * 2 + 0];
            vj1 += part[kc][m][c * 2 + 1];
        }
    }
    // ---- Center rows, write centered arrays + per-row D' stats ----
    {
        float su = block_sum(vi0, red);
        float fc = vi0 - su * (1.f / 256.f);
        fi[i0 * 256 + t] = fc;
        float d = block_sum(fc * u, red);
        float sv = block_sum(vj0, red);
        float gcj = vj0 - sv * (1.f / 256.f);
        fjb[i0 * 256 + t] = gcj;
        float dj = block_sum(gcj * u, red);
        if (t == 0) {
            stats[i0 * 8 + 1] = d;
            stats[i0 * 8 + 3] = dj;
        }
        su = block_sum(vi1, red);
        fc = vi1 - su * (1.f / 256.f);
        fi[(i0 + 1) * 256 + t] = fc;
        d = block_sum(fc * u, red);
        sv = block_sum(vj1, red);
        gcj = vj1 - sv * (1.f / 256.f);
        fjb[(i0 + 1) * 256 + t] = gcj;
        dj = block_sum(gcj * u, red);
        if (t == 0) {
            stats[(i0 + 1) * 8 + 1] = d;
            stats[(i0 + 1) * 8 + 3] = dj;
        }
    }
}

// 8-elem packed mish+dot body; xc = fic+fjc is already centered, so
// y = (xc*rs)*G' + E'. One rcp per 8 elems (v >= 2 always; overflow would
// need sum of positive z > 44 across 8 LN'd elems -- impossible).
// Reads xiA/xiB, gA..wB, two2 from enclosing scope; xj from LDS ptr XJP.
#define MISH8(XJP, RS2, ACC0, ACC1)                                          \
    do {                                                                      \
        v4f xjA = *(const v4f*)(XJP);                                         \
        v4f xjB = *(const v4f*)((XJP) + 4);                                   \
        v2f xs0 = pk_add(LO2(xiA), LO2(xjA));                                 \
        v2f xs1 = pk_add(HI2(xiA), HI2(xjA));                                 \
        v2f xs2 = pk_add(LO2(xiB), LO2(xjB));                                 \
        v2f xs3 = pk_add(HI2(xiB), HI2(xjB));                                 \
        v2f y0 = pk_fma(pk_mul(xs0, RS2), LO2(gA), LO2(eA));                  \
        v2f y1 = pk_fma(pk_mul(xs1, RS2), HI2(gA), HI2(eA));                  \
        v2f y2 = pk_fma(pk_mul(xs2, RS2), LO2(gB), LO2(eB));                  \
        v2f y3 = pk_fma(pk_mul(xs3, RS2), HI2(gB), HI2(eB));                  \
        v2f t0, t1, t2, t3;                                                   \
        t0.x = __builtin_amdgcn_exp2f(y0.x); t0.y = __builtin_amdgcn_exp2f(y0.y); \
        t1.x = __builtin_amdgcn_exp2f(y1.x); t1.y = __builtin_amdgcn_exp2f(y1.y); \
        t2.x = __builtin_amdgcn_exp2f(y2.x); t2.y = __builtin_amdgcn_exp2f(y2.y); \
        t3.x = __builtin_amdgcn_exp2f(y3.x); t3.y = __builtin_amdgcn_exp2f(y3.y); \
        v2f v0 = pk_fma(t0, pk_add(t0, two2), two2);                          \
        v2f v1 = pk_fma(t1, pk_add(t1, two2), two2);                          \
        v2f v2_ = pk_fma(t2, pk_add(t2, two2), two2);                         \
        v2f v3 = pk_fma(t3, pk_add(t3, two2), two2);                          \
        v2f Pab = pk_mul(v0, v1), Pcd = pk_mul(v2_, v3);                      \
        v2f Q = pk_mul(Pab, Pcd);                                             \
        float rall = __builtin_amdgcn_rcpf(Q.x * Q.y);                        \
        v2f R1; R1.x = rall * Q.y; R1.y = rall * Q.x;                         \
        v2f Rab = pk_mul(R1, Pcd), Rcd = pk_mul(R1, Pab);                     \
        v2f iv0 = pk_mul(Rab, v1);                                            \
        v2f iv1 = pk_mul(Rab, v0);                                            \
        v2f iv2 = pk_mul(Rcd, v3);                                            \
        v2f iv3 = pk_mul(Rcd, v2_);                                           \
        ACC0 = pk_fma(pk_mul(y0, iv0), LO2(wA), ACC0);                        \
        ACC1 = pk_fma(pk_mul(y1, iv1), HI2(wA), ACC1);                        \
        ACC0 = pk_fma(pk_mul(y2, iv2), LO2(wB), ACC0);                        \
        ACC1 = pk_fma(pk_mul(y3, iv3), HI2(wB), ACC1);                        \
    } while (0)

// 512 threads, 32i x 16j tile, EXACTLY 1 pair per thread (R8's per-thread
// body unchanged -- no shfl, no half-split). ti = tid>>4 spans 4 rows/wave
// (broadcast-free FI reads, same as R8); tj = tid&15 (free 2-way FJ).
// LDS = FI[32][260] + FJ[16][260] + G/E/W = 53 KB -> 3 blocks x 8 waves =
// 24 waves/CU (1.5x R8's 16) with identical per-pair arithmetic.
__global__ __launch_bounds__(512, 6) void k3_pair(
    const float* __restrict__ fi, const float* __restrict__ fjb,
    const float* __restrict__ stats,
    const float* __restrict__ Gp, const float* __restrict__ Ep,
    const float* __restrict__ Wp, const float* __restrict__ consts,
    const float* __restrict__ bc2, float* __restrict__ out, int write_mask) {
    __shared__ __align__(16) float FI[32][260];  // 2-way banks on reads (free)
    __shared__ __align__(16) float FJ[16][260];
    __shared__ __align__(16) float Gs[256], Es[256], Ws[256];
    const int tid = threadIdx.x;
    const int i0 = blockIdx.y * 32, j0 = blockIdx.x * 16;
#pragma unroll
    for (int l = 0; l < 4; ++l) {    // FI: 32 rows = 2048 quads, 512 threads
        int idx = tid + l * 512;
        int r = idx >> 6, c = (idx & 63) * 4;
        *(float4*)&FI[r][c] = *(const float4*)&fi[(i0 + r) * 256 + c];
    }
#pragma unroll
    for (int l = 0; l < 2; ++l) {    // FJ: 16 rows = 1024 quads
        int idx = tid + l * 512;
        int r = idx >> 6, c = (idx & 63) * 4;
        *(float4*)&FJ[r][c] = *(const float4*)&fjb[(j0 + r) * 256 + c];
    }
    if (tid < 256) {
        Gs[tid] = Gp[tid];
        Es[tid] = Ep[tid];
        Ws[tid] = Wp[tid];
    }
    const int ti = tid >> 4, tj = tid & 15;   // ti 0..31, tj 0..15
    const int i = i0 + ti, j = j0 + tj;
    const float Di = stats[i * 8 + 1];
    const float Dj = stats[j * 8 + 3];
    const float Sew = consts[0], bc2f = bc2[0];
    __syncthreads();
    const float* FIp = &FI[ti][0];
    const float* FJp = &FJ[tj][0];
    // pass 1: var = mean((fic+fjc)^2)  (sum of squares -> no cancellation)
    v2f sqa = {0.f, 0.f}, sqb = {0.f, 0.f};
#pragma unroll 8
    for (int d8 = 0; d8 < 32; ++d8) {
        v4f xiA = *(const v4f*)(FIp + d8 * 8);
        v4f xiB = *(const v4f*)(FIp + d8 * 8 + 4);
        v4f xjA = *(const v4f*)(FJp + d8 * 8);
        v4f xjB = *(const v4f*)(FJp + d8 * 8 + 4);
        v2f s0 = pk_add(LO2(xiA), LO2(xjA));
        v2f s1 = pk_add(HI2(xiA), HI2(xjA));
        v2f s2 = pk_add(LO2(xiB), LO2(xjB));
        v2f s3 = pk_add(HI2(xiB), HI2(xjB));
        sqa = pk_fma(s0, s0, sqa);
        sqb = pk_fma(s1, s1, sqb);
        sqa = pk_fma(s2, s2, sqa);
        sqb = pk_fma(s3, s3, sqb);
    }
    const float var = ((sqa.x + sqa.y) + (sqb.x + sqb.y)) * (1.f / 256.f);
    const float rs = __builtin_amdgcn_rsqf(var + EPS);
    const float lin = fmaf(rs, Di + Dj, Sew);
    // pass 2: nonlinear term
    const v4f* G4 = (const v4f*)&Gs[0];
    const v4f* E4 = (const v4f*)&Es[0];
    const v4f* W4 = (const v4f*)&Ws[0];
    const v2f rs2 = {rs, rs};
    const v2f two2 = {2.f, 2.f};
    v2f acc0 = {0.f, 0.f}, acc1 = {0.f, 0.f};
#pragma unroll 2
    for (int d8 = 0; d8 < 32; ++d8) {
        v4f xiA = *(const v4f*)(FIp + d8 * 8);
        v4f xiB = *(const v4f*)(FIp + d8 * 8 + 4);
        v4f gA = G4[d8 * 2], gB = G4[d8 * 2 + 1];
        v4f eA = E4[d8 * 2], eB = E4[d8 * 2 + 1];
        v4f wA = W4[d8 * 2], wB = W4[d8 * 2 + 1];
        MISH8(FJp + d8 * 8, rs2, acc0, acc1);
    }
    const float nl = (acc0.x + acc0.y) + (acc1.x + acc1.y);
    out[i * 768 + j] = fmaf(-2.f, nl, lin) + bc2f;
    if (write_mask) out[LOGITS_N + i * 768 + j] = 1.0f;
}

extern "C" void kernel_launch(void* const* d_in, const int* in_sizes, int n_in,
                              void* d_out, int out_size, void* d_ws, size_t ws_size,
                              hipStream_t stream) {
    const float* h   = (const float*)d_in[0];
    const float* W0  = (const float*)d_in[1];
    const float* b0  = (const float*)d_in[2];
    const float* g0  = (const float*)d_in[3];
    const float* be0 = (const float*)d_in[4];
    const float* W1  = (const float*)d_in[5];
    const float* b1  = (const float*)d_in[6];
    const float* Wc1 = (const float*)d_in[7];
    const float* bc1 = (const float*)d_in[8];
    const float* gc  = (const float*)d_in[9];
    const float* bec = (const float*)d_in[10];
    const float* Wc2 = (const float*)d_in[11];
    const float* bc2 = (const float*)d_in[12];
    float* ws = (float*)d_ws;
    float* fi     = ws;             // 768*256
    float* fjb    = ws + 196608;    // 768*256
    float* stats  = ws + 393216;    // 768*8
    float* Gp     = ws + 399360;    // 256
    float* Ep     = ws + 399616;    // 256
    float* Wp     = ws + 399872;    // 256
    float* consts = ws + 400128;    // 4
    float* out = (float*)d_out;
    int write_mask = (out_size >= 2 * LOGITS_N) ? 1 : 0;

    k1_rows<<<dim3(384), dim3(256), 0, stream>>>(h, W0, b0, g0, be0, W1, b1,
                                                 Wc1, bc1, gc, bec, Wc2,
                                                 fi, fjb, stats, Gp, Ep, Wp,
                                                 consts);
    k3_pair<<<dim3(48, 24), dim3(512), 0, stream>>>(fi, fjb, stats,
                                                    Gp, Ep, Wp, consts, bc2,
                                                    out, write_mask);
}

// Round 15
// 70.088 us; speedup vs baseline: 1.6200x; 1.0282x over previous
//
#include <hip/hip_runtime.h>

#define EPS 1e-5f
#define LOGITS_N (768 * 768)
#define LOG2E 1.4426950408889634f
#define LN2   0.6931471805599453f

typedef float v2f __attribute__((ext_vector_type(2)));
typedef float v4f __attribute__((ext_vector_type(4)));

// Packed fp32 ops (VOP3P) via inline asm.
__device__ __forceinline__ v2f pk_add(v2f a, v2f b) {
    v2f d; asm("v_pk_add_f32 %0, %1, %2" : "=v"(d) : "v"(a), "v"(b)); return d;
}
__device__ __forceinline__ v2f pk_mul(v2f a, v2f b) {
    v2f d; asm("v_pk_mul_f32 %0, %1, %2" : "=v"(d) : "v"(a), "v"(b)); return d;
}
__device__ __forceinline__ v2f pk_fma(v2f a, v2f b, v2f c) {
    v2f d; asm("v_pk_fma_f32 %0, %1, %2, %3" : "=v"(d) : "v"(a), "v"(b), "v"(c)); return d;
}
#define LO2(v) __builtin_shufflevector(v, v, 0, 1)
#define HI2(v) __builtin_shufflevector(v, v, 2, 3)

// mish(z) = z * tanh(softplus(z)); with t = e^z: mish = z*u/(u+2), u = t(t+2)
__device__ __forceinline__ float mishf(float z) {
    float t = __expf(fminf(z, 40.f));
    float u = t * (t + 2.f);
    return z * u * __builtin_amdgcn_rcpf(u + 2.f);
}

// block of 256 threads (4 waves); returns full sum to all threads
__device__ __forceinline__ float block_sum(float v, float* red) {
#pragma unroll
    for (int off = 32; off > 0; off >>= 1) v += __shfl_down(v, off, 64);
    const int lane = threadIdx.x & 63, wid = threadIdx.x >> 6;
    __syncthreads();
    if (lane == 0) red[wid] = v;
    __syncthreads();
    return red[0] + red[1] + red[2] + red[3];
}

// 2 rows per block (384 blocks). Coalesced float4 weight loads via k-split.
// Outputs CENTERED rows: fi = vi - mean(vi), fjb = (vj+bc1) - mean(vj+bc1),
// plus per-row D' = dot(centered, gc.*wc2). k3's pair variance is then just
// mean((fic+fjc)^2) -- computed in k3's pass 1 with no cross term at all.
__global__ __launch_bounds__(256) void k1_rows(
    const float* __restrict__ h, const float* __restrict__ W0,
    const float* __restrict__ b0, const float* __restrict__ g0,
    const float* __restrict__ be0, const float* __restrict__ W1,
    const float* __restrict__ b1, const float* __restrict__ Wc1,
    const float* __restrict__ bc1, const float* __restrict__ gc,
    const float* __restrict__ bec, const float* __restrict__ wc2,
    float* __restrict__ fi, float* __restrict__ fjb,
    float* __restrict__ stats, float* __restrict__ Gp,
    float* __restrict__ Ep, float* __restrict__ Wp,
    float* __restrict__ consts) {
    __shared__ float shi[256][2];
    __shared__ float sai[256][2];
    __shared__ float sHi[128][2];
    __shared__ float red[4];
    __shared__ float part[4][64][12];
    const int t = threadIdx.x;
    const int i0 = blockIdx.x * 2;
    const float u = gc[t] * wc2[t];
    if (blockIdx.x == 0) {
        Gp[t] = gc[t] * LOG2E;
        Ep[t] = bec[t] * LOG2E;
        Wp[t] = wc2[t] * LN2;
        float sew = block_sum(bec[t] * wc2[t], red);
        if (t == 0) { consts[0] = sew; }
    }
    shi[t][0] = h[i0 * 256 + t];
    shi[t][1] = h[i0 * 256 + 256 + t];
    __syncthreads();
    // ---- GEMM1: x[2][256] = h2 @ W0   (k-split 4 x 64, cols 4/thread) ----
    {
        const int kc = t >> 6, jg = t & 63;
        const float* w0p = W0 + (kc * 64) * 256 + jg * 4;
        float ax[2][4] = {};
#pragma unroll 8
        for (int kk = 0; kk < 64; ++kk) {
            float4 w = *(const float4*)(w0p + kk * 256);
            float2 hh = *(const float2*)&shi[kc * 64 + kk][0];
            ax[0][0] = fmaf(hh.x, w.x, ax[0][0]);
            ax[0][1] = fmaf(hh.x, w.y, ax[0][1]);
            ax[0][2] = fmaf(hh.x, w.z, ax[0][2]);
            ax[0][3] = fmaf(hh.x, w.w, ax[0][3]);
            ax[1][0] = fmaf(hh.y, w.x, ax[1][0]);
            ax[1][1] = fmaf(hh.y, w.y, ax[1][1]);
            ax[1][2] = fmaf(hh.y, w.z, ax[1][2]);
            ax[1][3] = fmaf(hh.y, w.w, ax[1][3]);
        }
        float* pp = &part[kc][jg][0];
#pragma unroll
        for (int c = 0; c < 4; ++c) { pp[c * 2] = ax[0][c]; pp[c * 2 + 1] = ax[1][c]; }
    }
    __syncthreads();
    float x0, x1;
    {
        const int m = t >> 2, c = t & 3;
        x0 = b0[t]; x1 = x0;
#pragma unroll
        for (int kc = 0; kc < 4; ++kc) {
            x0 += part[kc][m][c * 2 + 0];
            x1 += part[kc][m][c * 2 + 1];
        }
    }
    // ---- LN + mish per row ----
    {
        float s1 = block_sum(x0, red), s2 = block_sum(x0 * x0, red);
        float mean = s1 * (1.f / 256.f);
        float var = fmaxf(s2 * (1.f / 256.f) - mean * mean, 0.f);
        float rs = __builtin_amdgcn_rsqf(var + EPS);
        sai[t][0] = mishf((x0 - mean) * rs * g0[t] + be0[t]);
        s1 = block_sum(x1, red); s2 = block_sum(x1 * x1, red);
        mean = s1 * (1.f / 256.f);
        var = fmaxf(s2 * (1.f / 256.f) - mean * mean, 0.f);
        rs = __builtin_amdgcn_rsqf(var + EPS);
        sai[t][1] = mishf((x1 - mean) * rs * g0[t] + be0[t]);
    }
    __syncthreads();
    // ---- GEMM2: H[2][128] = a2 @ W1   (k-split 8 x 32, cols 4/thread) ----
    {
        const int kc = t >> 5, jg = t & 31;
        const float* w1p = W1 + (kc * 32) * 128 + jg * 4;
        float ah[2][4] = {};
#pragma unroll 8
        for (int kk = 0; kk < 32; ++kk) {
            float4 w = *(const float4*)(w1p + kk * 128);
            float2 ss = *(const float2*)&sai[kc * 32 + kk][0];
            ah[0][0] = fmaf(ss.x, w.x, ah[0][0]);
            ah[0][1] = fmaf(ss.x, w.y, ah[0][1]);
            ah[0][2] = fmaf(ss.x, w.z, ah[0][2]);
            ah[0][3] = fmaf(ss.x, w.w, ah[0][3]);
            ah[1][0] = fmaf(ss.y, w.x, ah[1][0]);
            ah[1][1] = fmaf(ss.y, w.y, ah[1][1]);
            ah[1][2] = fmaf(ss.y, w.z, ah[1][2]);
            ah[1][3] = fmaf(ss.y, w.w, ah[1][3]);
        }
        float* pp = &part[0][0][0] + (kc * 32 + jg) * 12;
#pragma unroll
        for (int c = 0; c < 4; ++c) { pp[c * 2] = ah[0][c]; pp[c * 2 + 1] = ah[1][c]; }
    }
    __syncthreads();
    {
        const int r = t >> 7, jj = t & 127;
        float hv = b1[jj];
        const float* pf = &part[0][0][0];
#pragma unroll
        for (int kc = 0; kc < 8; ++kc)
            hv += pf[(kc * 32 + (jj >> 2)) * 12 + (jj & 3) * 2 + r];
        sHi[jj][r] = hv;
    }
    __syncthreads();
    // ---- GEMM3: vi = H@Wi, vj = H@Wj (K=128, k-split 4 x 32) ----
    float avi[2][4] = {}, avj[2][4] = {};
    {
        const int kc = t >> 6, jg = t & 63;
        const float* wip = Wc1 + (kc * 32) * 256 + jg * 4;
        const float* wjp = Wc1 + (128 + kc * 32) * 256 + jg * 4;
#pragma unroll 4
        for (int kk = 0; kk < 32; ++kk) {
            float4 wa = *(const float4*)(wip + kk * 256);
            float4 wb = *(const float4*)(wjp + kk * 256);
            float2 hh = *(const float2*)&sHi[kc * 32 + kk][0];
            avi[0][0] = fmaf(hh.x, wa.x, avi[0][0]);
            avi[0][1] = fmaf(hh.x, wa.y, avi[0][1]);
            avi[0][2] = fmaf(hh.x, wa.z, avi[0][2]);
            avi[0][3] = fmaf(hh.x, wa.w, avi[0][3]);
            avi[1][0] = fmaf(hh.y, wa.x, avi[1][0]);
            avi[1][1] = fmaf(hh.y, wa.y, avi[1][1]);
            avi[1][2] = fmaf(hh.y, wa.z, avi[1][2]);
            avi[1][3] = fmaf(hh.y, wa.w, avi[1][3]);
            avj[0][0] = fmaf(hh.x, wb.x, avj[0][0]);
            avj[0][1] = fmaf(hh.x, wb.y, avj[0][1]);
            avj[0][2] = fmaf(hh.x, wb.z, avj[0][2]);
            avj[0][3] = fmaf(hh.x, wb.w, avj[0][3]);
            avj[1][0] = fmaf(hh.y, wb.x, avj[1][0]);
            avj[1][1] = fmaf(hh.y, wb.y, avj[1][1]);
            avj[1][2] = fmaf(hh.y, wb.z, avj[1][2]);
            avj[1][3] = fmaf(hh.y, wb.w, avj[1][3]);
        }
        float* pp = &part[kc][jg][0];
#pragma unroll
        for (int c = 0; c < 4; ++c) { pp[c * 2] = avi[0][c]; pp[c * 2 + 1] = avi[1][c]; }
    }
    __syncthreads();
    float vi0 = 0.f, vi1 = 0.f;
    {
        const int m = t >> 2, c = t & 3;
#pragma unroll
        for (int kc = 0; kc < 4; ++kc) {
            vi0 += part[kc][m][c * 2 + 0];
            vi1 += part[kc][m][c * 2 + 1];
        }
    }
    __syncthreads();
    {
        const int kc = t >> 6, jg = t & 63;
        float* pp = &part[kc][jg][0];
#pragma unroll
        for (int c = 0; c < 4; ++c) { pp[c * 2] = avj[0][c]; pp[c * 2 + 1] = avj[1][c]; }
    }
    __syncthreads();
    float vj0, vj1;
    {
        const int m = t >> 2, c = t & 3;
        vj0 = bc1[t]; vj1 = vj0;
#pragma unroll
        for (int kc = 0; kc < 4; ++kc) {
            vj0 += part[kc][m][c * 2 + 0];
            vj1 += part[kc][m][c * 2 + 1];
        }
    }
    // ---- Center rows, write centered arrays + per-row D' stats ----
    {
        float su = block_sum(vi0, red);
        float fc = vi0 - su * (1.f / 256.f);
        fi[i0 * 256 + t] = fc;
        float d = block_sum(fc * u, red);
        float sv = block_sum(vj0, red);
        float gcj = vj0 - sv * (1.f / 256.f);
        fjb[i0 * 256 + t] = gcj;
        float dj = block_sum(gcj * u, red);
        if (t == 0) {
            stats[i0 * 8 + 1] = d;
            stats[i0 * 8 + 3] = dj;
        }
        su = block_sum(vi1, red);
        fc = vi1 - su * (1.f / 256.f);
        fi[(i0 + 1) * 256 + t] = fc;
        d = block_sum(fc * u, red);
        sv = block_sum(vj1, red);
        gcj = vj1 - sv * (1.f / 256.f);
        fjb[(i0 + 1) * 256 + t] = gcj;
        dj = block_sum(gcj * u, red);
        if (t == 0) {
            stats[(i0 + 1) * 8 + 1] = d;
            stats[(i0 + 1) * 8 + 3] = dj;
        }
    }
}

// 8-elem mish+dot body. Front end (xs, y, t, v) is R8's proven pk-asm code,
// operands UNCHANGED. Tail is PURE SCALAR C (no values constructed here ever
// enter an asm operand -- R14's insert-built v2f -> pk-asm path miscompiled):
// per-element v_rcp_f32 on the near-idle trans pipe replaces the 12-pk-op
// (48 VALU-exec-cycle) reciprocal-of-product unwind. v >= 2 always.
// Accumulates into scalar AS0..AS3 from enclosing scope.
#define MISH8(XJP, RS2)                                                       \
    do {                                                                      \
        v4f xjA = *(const v4f*)(XJP);                                         \
        v4f xjB = *(const v4f*)((XJP) + 4);                                   \
        v2f xs0 = pk_add(LO2(xiA), LO2(xjA));                                 \
        v2f xs1 = pk_add(HI2(xiA), HI2(xjA));                                 \
        v2f xs2 = pk_add(LO2(xiB), LO2(xjB));                                 \
        v2f xs3 = pk_add(HI2(xiB), HI2(xjB));                                 \
        v2f y0 = pk_fma(pk_mul(xs0, RS2), LO2(gA), LO2(eA));                  \
        v2f y1 = pk_fma(pk_mul(xs1, RS2), HI2(gA), HI2(eA));                  \
        v2f y2 = pk_fma(pk_mul(xs2, RS2), LO2(gB), LO2(eB));                  \
        v2f y3 = pk_fma(pk_mul(xs3, RS2), HI2(gB), HI2(eB));                  \
        v2f t0, t1, t2, t3;                                                   \
        t0.x = __builtin_amdgcn_exp2f(y0.x); t0.y = __builtin_amdgcn_exp2f(y0.y); \
        t1.x = __builtin_amdgcn_exp2f(y1.x); t1.y = __builtin_amdgcn_exp2f(y1.y); \
        t2.x = __builtin_amdgcn_exp2f(y2.x); t2.y = __builtin_amdgcn_exp2f(y2.y); \
        t3.x = __builtin_amdgcn_exp2f(y3.x); t3.y = __builtin_amdgcn_exp2f(y3.y); \
        v2f v0 = pk_fma(t0, pk_add(t0, two2), two2);                          \
        v2f v1 = pk_fma(t1, pk_add(t1, two2), two2);                          \
        v2f v2_ = pk_fma(t2, pk_add(t2, two2), two2);                         \
        v2f v3 = pk_fma(t3, pk_add(t3, two2), two2);                          \
        AS0 = fmaf(y0.x * __builtin_amdgcn_rcpf(v0.x),  wA.x, AS0);           \
        AS1 = fmaf(y0.y * __builtin_amdgcn_rcpf(v0.y),  wA.y, AS1);           \
        AS2 = fmaf(y1.x * __builtin_amdgcn_rcpf(v1.x),  wA.z, AS2);           \
        AS3 = fmaf(y1.y * __builtin_amdgcn_rcpf(v1.y),  wA.w, AS3);           \
        AS0 = fmaf(y2.x * __builtin_amdgcn_rcpf(v2_.x), wB.x, AS0);           \
        AS1 = fmaf(y2.y * __builtin_amdgcn_rcpf(v2_.y), wB.y, AS1);           \
        AS2 = fmaf(y3.x * __builtin_amdgcn_rcpf(v3.x),  wB.z, AS2);           \
        AS3 = fmaf(y3.y * __builtin_amdgcn_rcpf(v3.y),  wB.w, AS3);           \
    } while (0)

// R8's proven kernel: 16x16 tile, 1 pair/thread, all operands from LDS.
// Pass 1: var = mean((fic+fjc)^2) -- perfectly conditioned, NO cross term.
// Pass 2: logits = rs*(Di+Dj) + Sew - 2*sum_d (y/v)*w' + bc2.
__global__ __launch_bounds__(256, 4) void k3_pair(
    const float* __restrict__ fi, const float* __restrict__ fjb,
    const float* __restrict__ stats,
    const float* __restrict__ Gp, const float* __restrict__ Ep,
    const float* __restrict__ Wp, const float* __restrict__ consts,
    const float* __restrict__ bc2, float* __restrict__ out, int write_mask) {
    __shared__ __align__(16) float FI[16][260];  // 2-way banks on reads (free)
    __shared__ __align__(16) float FJ[16][260];
    __shared__ __align__(16) float Gs[256], Es[256], Ws[256];
    const int tid = threadIdx.x;
    const int i0 = blockIdx.y * 16, j0 = blockIdx.x * 16;
#pragma unroll
    for (int l = 0; l < 4; ++l) {
        int idx = tid + l * 256;
        int r = idx >> 6, c = (idx & 63) * 4;
        *(float4*)&FI[r][c] = *(const float4*)&fi[(i0 + r) * 256 + c];
        *(float4*)&FJ[r][c] = *(const float4*)&fjb[(j0 + r) * 256 + c];
    }
    Gs[tid] = Gp[tid];
    Es[tid] = Ep[tid];
    Ws[tid] = Wp[tid];
    const int ti = tid >> 4, tj = tid & 15;
    const int i = i0 + ti, j = j0 + tj;
    const float Di = stats[i * 8 + 1];
    const float Dj = stats[j * 8 + 3];
    const float Sew = consts[0], bc2f = bc2[0];
    __syncthreads();
    const float* FIp = &FI[ti][0];
    const float* FJp = &FJ[tj][0];
    // pass 1: var = mean((fic+fjc)^2)  (sum of squares -> no cancellation)
    v2f sqa = {0.f, 0.f}, sqb = {0.f, 0.f};
#pragma unroll 8
    for (int d8 = 0; d8 < 32; ++d8) {
        v4f xiA = *(const v4f*)(FIp + d8 * 8);
        v4f xiB = *(const v4f*)(FIp + d8 * 8 + 4);
        v4f xjA = *(const v4f*)(FJp + d8 * 8);
        v4f xjB = *(const v4f*)(FJp + d8 * 8 + 4);
        v2f s0 = pk_add(LO2(xiA), LO2(xjA));
        v2f s1 = pk_add(HI2(xiA), HI2(xjA));
        v2f s2 = pk_add(LO2(xiB), LO2(xjB));
        v2f s3 = pk_add(HI2(xiB), HI2(xjB));
        sqa = pk_fma(s0, s0, sqa);
        sqb = pk_fma(s1, s1, sqb);
        sqa = pk_fma(s2, s2, sqa);
        sqb = pk_fma(s3, s3, sqb);
    }
    const float var = ((sqa.x + sqa.y) + (sqb.x + sqb.y)) * (1.f / 256.f);
    const float rs = __builtin_amdgcn_rsqf(var + EPS);
    const float lin = fmaf(rs, Di + Dj, Sew);
    // pass 2: nonlinear term (scalar accumulators AS0..AS3)
    const v4f* G4 = (const v4f*)&Gs[0];
    const v4f* E4 = (const v4f*)&Es[0];
    const v4f* W4 = (const v4f*)&Ws[0];
    const v2f rs2 = {rs, rs};
    const v2f two2 = {2.f, 2.f};
    float AS0 = 0.f, AS1 = 0.f, AS2 = 0.f, AS3 = 0.f;
#pragma unroll 2
    for (int d8 = 0; d8 < 32; ++d8) {
        v4f xiA = *(const v4f*)(FIp + d8 * 8);
        v4f xiB = *(const v4f*)(FIp + d8 * 8 + 4);
        v4f gA = G4[d8 * 2], gB = G4[d8 * 2 + 1];
        v4f eA = E4[d8 * 2], eB = E4[d8 * 2 + 1];
        v4f wA = W4[d8 * 2], wB = W4[d8 * 2 + 1];
        MISH8(FJp + d8 * 8, rs2);
    }
    const float nl = (AS0 + AS1) + (AS2 + AS3);
    out[i * 768 + j] = fmaf(-2.f, nl, lin) + bc2f;
    if (write_mask) out[LOGITS_N + i * 768 + j] = 1.0f;
}

extern "C" void kernel_launch(void* const* d_in, const int* in_sizes, int n_in,
                              void* d_out, int out_size, void* d_ws, size_t ws_size,
                              hipStream_t stream) {
    const float* h   = (const float*)d_in[0];
    const float* W0  = (const float*)d_in[1];
    const float* b0  = (const float*)d_in[2];
    const float* g0  = (const float*)d_in[3];
    const float* be0 = (const float*)d_in[4];
    const float* W1  = (const float*)d_in[5];
    const float* b1  = (const float*)d_in[6];
    const float* Wc1 = (const float*)d_in[7];
    const float* bc1 = (const float*)d_in[8];
    const float* gc  = (const float*)d_in[9];
    const float* bec = (const float*)d_in[10];
    const float* Wc2 = (const float*)d_in[11];
    const float* bc2 = (const float*)d_in[12];
    float* ws = (float*)d_ws;
    float* fi     = ws;             // 768*256
    float* fjb    = ws + 196608;    // 768*256
    float* stats  = ws + 393216;    // 768*8
    float* Gp     = ws + 399360;    // 256
    float* Ep     = ws + 399616;    // 256
    float* Wp     = ws + 399872;    // 256
    float* consts = ws + 400128;    // 4
    float* out = (float*)d_out;
    int write_mask = (out_size >= 2 * LOGITS_N) ? 1 : 0;

    k1_rows<<<dim3(384), dim3(256), 0, stream>>>(h, W0, b0, g0, be0, W1, b1,
                                                 Wc1, bc1, gc, bec, Wc2,
                                                 fi, fjb, stats, Gp, Ep, Wp,
                                                 consts);
    k3_pair<<<dim3(48, 48), dim3(256), 0, stream>>>(fi, fjb, stats,
                                                    Gp, Ep, Wp, consts, bc2,
                                                    out, write_mask);
}

// Round 16
// 67.322 us; speedup vs baseline: 1.6865x; 1.0411x over previous
//
#include <hip/hip_runtime.h>

#define EPS 1e-5f
#define LOGITS_N (768 * 768)
#define LOG2E 1.4426950408889634f
#define LN2   0.6931471805599453f

typedef float v2f __attribute__((ext_vector_type(2)));
typedef float v4f __attribute__((ext_vector_type(4)));

// Packed fp32 ops (VOP3P) via inline asm.
__device__ __forceinline__ v2f pk_add(v2f a, v2f b) {
    v2f d; asm("v_pk_add_f32 %0, %1, %2" : "=v"(d) : "v"(a), "v"(b)); return d;
}
__device__ __forceinline__ v2f pk_mul(v2f a, v2f b) {
    v2f d; asm("v_pk_mul_f32 %0, %1, %2" : "=v"(d) : "v"(a), "v"(b)); return d;
}
__device__ __forceinline__ v2f pk_fma(v2f a, v2f b, v2f c) {
    v2f d; asm("v_pk_fma_f32 %0, %1, %2, %3" : "=v"(d) : "v"(a), "v"(b), "v"(c)); return d;
}
#define LO2(v) __builtin_shufflevector(v, v, 0, 1)
#define HI2(v) __builtin_shufflevector(v, v, 2, 3)

// mish(z) = z * tanh(softplus(z)); with t = e^z: mish = z*u/(u+2), u = t(t+2)
__device__ __forceinline__ float mishf(float z) {
    float t = __expf(fminf(z, 40.f));
    float u = t * (t + 2.f);
    return z * u * __builtin_amdgcn_rcpf(u + 2.f);
}

// block of 256 threads (4 waves); returns full sum to all threads
__device__ __forceinline__ float block_sum(float v, float* red) {
#pragma unroll
    for (int off = 32; off > 0; off >>= 1) v += __shfl_down(v, off, 64);
    const int lane = threadIdx.x & 63, wid = threadIdx.x >> 6;
    __syncthreads();
    if (lane == 0) red[wid] = v;
    __syncthreads();
    return red[0] + red[1] + red[2] + red[3];
}

// 2 rows per block (384 blocks). Coalesced float4 weight loads via k-split.
// Outputs CENTERED rows: fi = vi - mean(vi), fjb = (vj+bc1) - mean(vj+bc1),
// plus per-row D' = dot(centered, gc.*wc2). k3's pair variance is then just
// mean((fic+fjc)^2) -- computed in k3's pass 1 with no cross term at all.
__global__ __launch_bounds__(256) void k1_rows(
    const float* __restrict__ h, const float* __restrict__ W0,
    const float* __restrict__ b0, const float* __restrict__ g0,
    const float* __restrict__ be0, const float* __restrict__ W1,
    const float* __restrict__ b1, const float* __restrict__ Wc1,
    const float* __restrict__ bc1, const float* __restrict__ gc,
    const float* __restrict__ bec, const float* __restrict__ wc2,
    float* __restrict__ fi, float* __restrict__ fjb,
    float* __restrict__ stats, float* __restrict__ Gp,
    float* __restrict__ Ep, float* __restrict__ Wp,
    float* __restrict__ consts) {
    __shared__ float shi[256][2];
    __shared__ float sai[256][2];
    __shared__ float sHi[128][2];
    __shared__ float red[4];
    __shared__ float part[4][64][12];
    const int t = threadIdx.x;
    const int i0 = blockIdx.x * 2;
    const float u = gc[t] * wc2[t];
    if (blockIdx.x == 0) {
        Gp[t] = gc[t] * LOG2E;
        Ep[t] = bec[t] * LOG2E;
        Wp[t] = wc2[t] * LN2;
        float sew = block_sum(bec[t] * wc2[t], red);
        if (t == 0) { consts[0] = sew; }
    }
    shi[t][0] = h[i0 * 256 + t];
    shi[t][1] = h[i0 * 256 + 256 + t];
    __syncthreads();
    // ---- GEMM1: x[2][256] = h2 @ W0   (k-split 4 x 64, cols 4/thread) ----
    {
        const int kc = t >> 6, jg = t & 63;
        const float* w0p = W0 + (kc * 64) * 256 + jg * 4;
        float ax[2][4] = {};
#pragma unroll 8
        for (int kk = 0; kk < 64; ++kk) {
            float4 w = *(const float4*)(w0p + kk * 256);
            float2 hh = *(const float2*)&shi[kc * 64 + kk][0];
            ax[0][0] = fmaf(hh.x, w.x, ax[0][0]);
            ax[0][1] = fmaf(hh.x, w.y, ax[0][1]);
            ax[0][2] = fmaf(hh.x, w.z, ax[0][2]);
            ax[0][3] = fmaf(hh.x, w.w, ax[0][3]);
            ax[1][0] = fmaf(hh.y, w.x, ax[1][0]);
            ax[1][1] = fmaf(hh.y, w.y, ax[1][1]);
            ax[1][2] = fmaf(hh.y, w.z, ax[1][2]);
            ax[1][3] = fmaf(hh.y, w.w, ax[1][3]);
        }
        float* pp = &part[kc][jg][0];
#pragma unroll
        for (int c = 0; c < 4; ++c) { pp[c * 2] = ax[0][c]; pp[c * 2 + 1] = ax[1][c]; }
    }
    __syncthreads();
    float x0, x1;
    {
        const int m = t >> 2, c = t & 3;
        x0 = b0[t]; x1 = x0;
#pragma unroll
        for (int kc = 0; kc < 4; ++kc) {
            x0 += part[kc][m][c * 2 + 0];
            x1 += part[kc][m][c * 2 + 1];
        }
    }
    // ---- LN + mish per row ----
    {
        float s1 = block_sum(x0, red), s2 = block_sum(x0 * x0, red);
        float mean = s1 * (1.f / 256.f);
        float var = fmaxf(s2 * (1.f / 256.f) - mean * mean, 0.f);
        float rs = __builtin_amdgcn_rsqf(var + EPS);
        sai[t][0] = mishf((x0 - mean) * rs * g0[t] + be0[t]);
        s1 = block_sum(x1, red); s2 = block_sum(x1 * x1, red);
        mean = s1 * (1.f / 256.f);
        var = fmaxf(s2 * (1.f / 256.f) - mean * mean, 0.f);
        rs = __builtin_amdgcn_rsqf(var + EPS);
        sai[t][1] = mishf((x1 - mean) * rs * g0[t] + be0[t]);
    }
    __syncthreads();
    // ---- GEMM2: H[2][128] = a2 @ W1   (k-split 8 x 32, cols 4/thread) ----
    {
        const int kc = t >> 5, jg = t & 31;
        const float* w1p = W1 + (kc * 32) * 128 + jg * 4;
        float ah[2][4] = {};
#pragma unroll 8
        for (int kk = 0; kk < 32; ++kk) {
            float4 w = *(const float4*)(w1p + kk * 128);
            float2 ss = *(const float2*)&sai[kc * 32 + kk][0];
            ah[0][0] = fmaf(ss.x, w.x, ah[0][0]);
            ah[0][1] = fmaf(ss.x, w.y, ah[0][1]);
            ah[0][2] = fmaf(ss.x, w.z, ah[0][2]);
            ah[0][3] = fmaf(ss.x, w.w, ah[0][3]);
            ah[1][0] = fmaf(ss.y, w.x, ah[1][0]);
            ah[1][1] = fmaf(ss.y, w.y, ah[1][1]);
            ah[1][2] = fmaf(ss.y, w.z, ah[1][2]);
            ah[1][3] = fmaf(ss.y, w.w, ah[1][3]);
        }
        float* pp = &part[0][0][0] + (kc * 32 + jg) * 12;
#pragma unroll
        for (int c = 0; c < 4; ++c) { pp[c * 2] = ah[0][c]; pp[c * 2 + 1] = ah[1][c]; }
    }
    __syncthreads();
    {
        const int r = t >> 7, jj = t & 127;
        float hv = b1[jj];
        const float* pf = &part[0][0][0];
#pragma unroll
        for (int kc = 0; kc < 8; ++kc)
            hv += pf[(kc * 32 + (jj >> 2)) * 12 + (jj & 3) * 2 + r];
        sHi[jj][r] = hv;
    }
    __syncthreads();
    // ---- GEMM3: vi = H@Wi, vj = H@Wj (K=128, k-split 4 x 32) ----
    float avi[2][4] = {}, avj[2][4] = {};
    {
        const int kc = t >> 6, jg = t & 63;
        const float* wip = Wc1 + (kc * 32) * 256 + jg * 4;
        const float* wjp = Wc1 + (128 + kc * 32) * 256 + jg * 4;
#pragma unroll 4
        for (int kk = 0; kk < 32; ++kk) {
            float4 wa = *(const float4*)(wip + kk * 256);
            float4 wb = *(const float4*)(wjp + kk * 256);
            float2 hh = *(const float2*)&sHi[kc * 32 + kk][0];
            avi[0][0] = fmaf(hh.x, wa.x, avi[0][0]);
            avi[0][1] = fmaf(hh.x, wa.y, avi[0][1]);
            avi[0][2] = fmaf(hh.x, wa.z, avi[0][2]);
            avi[0][3] = fmaf(hh.x, wa.w, avi[0][3]);
            avi[1][0] = fmaf(hh.y, wa.x, avi[1][0]);
            avi[1][1] = fmaf(hh.y, wa.y, avi[1][1]);
            avi[1][2] = fmaf(hh.y, wa.z, avi[1][2]);
            avi[1][3] = fmaf(hh.y, wa.w, avi[1][3]);
            avj[0][0] = fmaf(hh.x, wb.x, avj[0][0]);
            avj[0][1] = fmaf(hh.x, wb.y, avj[0][1]);
            avj[0][2] = fmaf(hh.x, wb.z, avj[0][2]);
            avj[0][3] = fmaf(hh.x, wb.w, avj[0][3]);
            avj[1][0] = fmaf(hh.y, wb.x, avj[1][0]);
            avj[1][1] = fmaf(hh.y, wb.y, avj[1][1]);
            avj[1][2] = fmaf(hh.y, wb.z, avj[1][2]);
            avj[1][3] = fmaf(hh.y, wb.w, avj[1][3]);
        }
        float* pp = &part[kc][jg][0];
#pragma unroll
        for (int c = 0; c < 4; ++c) { pp[c * 2] = avi[0][c]; pp[c * 2 + 1] = avi[1][c]; }
    }
    __syncthreads();
    float vi0 = 0.f, vi1 = 0.f;
    {
        const int m = t >> 2, c = t & 3;
#pragma unroll
        for (int kc = 0; kc < 4; ++kc) {
            vi0 += part[kc][m][c * 2 + 0];
            vi1 += part[kc][m][c * 2 + 1];
        }
    }
    __syncthreads();
    {
        const int kc = t >> 6, jg = t & 63;
        float* pp = &part[kc][jg][0];
#pragma unroll
        for (int c = 0; c < 4; ++c) { pp[c * 2] = avj[0][c]; pp[c * 2 + 1] = avj[1][c]; }
    }
    __syncthreads();
    float vj0, vj1;
    {
        const int m = t >> 2, c = t & 3;
        vj0 = bc1[t]; vj1 = vj0;
#pragma unroll
        for (int kc = 0; kc < 4; ++kc) {
            vj0 += part[kc][m][c * 2 + 0];
            vj1 += part[kc][m][c * 2 + 1];
        }
    }
    // ---- Center rows, write centered arrays + per-row D' stats ----
    {
        float su = block_sum(vi0, red);
        float fc = vi0 - su * (1.f / 256.f);
        fi[i0 * 256 + t] = fc;
        float d = block_sum(fc * u, red);
        float sv = block_sum(vj0, red);
        float gcj = vj0 - sv * (1.f / 256.f);
        fjb[i0 * 256 + t] = gcj;
        float dj = block_sum(gcj * u, red);
        if (t == 0) {
            stats[i0 * 8 + 1] = d;
            stats[i0 * 8 + 3] = dj;
        }
        su = block_sum(vi1, red);
        fc = vi1 - su * (1.f / 256.f);
        fi[(i0 + 1) * 256 + t] = fc;
        d = block_sum(fc * u, red);
        sv = block_sum(vj1, red);
        gcj = vj1 - sv * (1.f / 256.f);
        fjb[(i0 + 1) * 256 + t] = gcj;
        dj = block_sum(gcj * u, red);
        if (t == 0) {
            stats[(i0 + 1) * 8 + 1] = d;
            stats[(i0 + 1) * 8 + 3] = dj;
        }
    }
}

// 8-elem packed mish+dot body; xc = fic+fjc is already centered, so
// y = (xc*rs)*G' + E'. One rcp per 8 elems (v >= 2 always; overflow would
// need sum of positive z > 44 across 8 LN'd elems -- impossible). This
// trans/VALU balance (9 trans vs ~46 VALU-exec ops per 8 elems) measured
// best: per-element rcp (R15) tipped the kernel trans-bound and regressed.
#define MISH8(XJP, RS2, ACC0, ACC1)                                          \
    do {                                                                      \
        v4f xjA = *(const v4f*)(XJP);                                         \
        v4f xjB = *(const v4f*)((XJP) + 4);                                   \
        v2f xs0 = pk_add(LO2(xiA), LO2(xjA));                                 \
        v2f xs1 = pk_add(HI2(xiA), HI2(xjA));                                 \
        v2f xs2 = pk_add(LO2(xiB), LO2(xjB));                                 \
        v2f xs3 = pk_add(HI2(xiB), HI2(xjB));                                 \
        v2f y0 = pk_fma(pk_mul(xs0, RS2), LO2(gA), LO2(eA));                  \
        v2f y1 = pk_fma(pk_mul(xs1, RS2), HI2(gA), HI2(eA));                  \
        v2f y2 = pk_fma(pk_mul(xs2, RS2), LO2(gB), LO2(eB));                  \
        v2f y3 = pk_fma(pk_mul(xs3, RS2), HI2(gB), HI2(eB));                  \
        v2f t0, t1, t2, t3;                                                   \
        t0.x = __builtin_amdgcn_exp2f(y0.x); t0.y = __builtin_amdgcn_exp2f(y0.y); \
        t1.x = __builtin_amdgcn_exp2f(y1.x); t1.y = __builtin_amdgcn_exp2f(y1.y); \
        t2.x = __builtin_amdgcn_exp2f(y2.x); t2.y = __builtin_amdgcn_exp2f(y2.y); \
        t3.x = __builtin_amdgcn_exp2f(y3.x); t3.y = __builtin_amdgcn_exp2f(y3.y); \
        v2f v0 = pk_fma(t0, pk_add(t0, two2), two2);                          \
        v2f v1 = pk_fma(t1, pk_add(t1, two2), two2);                          \
        v2f v2_ = pk_fma(t2, pk_add(t2, two2), two2);                         \
        v2f v3 = pk_fma(t3, pk_add(t3, two2), two2);                          \
        v2f Pab = pk_mul(v0, v1), Pcd = pk_mul(v2_, v3);                      \
        v2f Q = pk_mul(Pab, Pcd);                                             \
        float rall = __builtin_amdgcn_rcpf(Q.x * Q.y);                        \
        v2f R1; R1.x = rall * Q.y; R1.y = rall * Q.x;                         \
        v2f Rab = pk_mul(R1, Pcd), Rcd = pk_mul(R1, Pab);                     \
        v2f iv0 = pk_mul(Rab, v1);                                            \
        v2f iv1 = pk_mul(Rab, v0);                                            \
        v2f iv2 = pk_mul(Rcd, v3);                                            \
        v2f iv3 = pk_mul(Rcd, v2_);                                           \
        ACC0 = pk_fma(pk_mul(y0, iv0), LO2(wA), ACC0);                        \
        ACC1 = pk_fma(pk_mul(y1, iv1), HI2(wA), ACC1);                        \
        ACC0 = pk_fma(pk_mul(y2, iv2), LO2(wB), ACC0);                        \
        ACC1 = pk_fma(pk_mul(y3, iv3), HI2(wB), ACC1);                        \
    } while (0)

// R8 optimum: 16x16 tile, 1 pair/thread, all operands from LDS.
// Pass 1: var = mean((fic+fjc)^2) -- perfectly conditioned, NO cross term
// (expanding the square reintroduces catastrophic cancellation -- verified).
// Pass 2: logits = rs*(Di+Dj) + Sew - 2*sum_d (y/v)*w' + bc2.
__global__ __launch_bounds__(256, 4) void k3_pair(
    const float* __restrict__ fi, const float* __restrict__ fjb,
    const float* __restrict__ stats,
    const float* __restrict__ Gp, const float* __restrict__ Ep,
    const float* __restrict__ Wp, const float* __restrict__ consts,
    const float* __restrict__ bc2, float* __restrict__ out, int write_mask) {
    __shared__ __align__(16) float FI[16][260];  // 2-way banks on reads (free)
    __shared__ __align__(16) float FJ[16][260];
    __shared__ __align__(16) float Gs[256], Es[256], Ws[256];
    const int tid = threadIdx.x;
    const int i0 = blockIdx.y * 16, j0 = blockIdx.x * 16;
#pragma unroll
    for (int l = 0; l < 4; ++l) {
        int idx = tid + l * 256;
        int r = idx >> 6, c = (idx & 63) * 4;
        *(float4*)&FI[r][c] = *(const float4*)&fi[(i0 + r) * 256 + c];
        *(float4*)&FJ[r][c] = *(const float4*)&fjb[(j0 + r) * 256 + c];
    }
    Gs[tid] = Gp[tid];
    Es[tid] = Ep[tid];
    Ws[tid] = Wp[tid];
    const int ti = tid >> 4, tj = tid & 15;
    const int i = i0 + ti, j = j0 + tj;
    const float Di = stats[i * 8 + 1];
    const float Dj = stats[j * 8 + 3];
    const float Sew = consts[0], bc2f = bc2[0];
    __syncthreads();
    const float* FIp = &FI[ti][0];
    const float* FJp = &FJ[tj][0];
    // pass 1: var = mean((fic+fjc)^2)  (sum of squares -> no cancellation)
    v2f sqa = {0.f, 0.f}, sqb = {0.f, 0.f};
#pragma unroll 8
    for (int d8 = 0; d8 < 32; ++d8) {
        v4f xiA = *(const v4f*)(FIp + d8 * 8);
        v4f xiB = *(const v4f*)(FIp + d8 * 8 + 4);
        v4f xjA = *(const v4f*)(FJp + d8 * 8);
        v4f xjB = *(const v4f*)(FJp + d8 * 8 + 4);
        v2f s0 = pk_add(LO2(xiA), LO2(xjA));
        v2f s1 = pk_add(HI2(xiA), HI2(xjA));
        v2f s2 = pk_add(LO2(xiB), LO2(xjB));
        v2f s3 = pk_add(HI2(xiB), HI2(xjB));
        sqa = pk_fma(s0, s0, sqa);
        sqb = pk_fma(s1, s1, sqb);
        sqa = pk_fma(s2, s2, sqa);
        sqb = pk_fma(s3, s3, sqb);
    }
    const float var = ((sqa.x + sqa.y) + (sqb.x + sqb.y)) * (1.f / 256.f);
    const float rs = __builtin_amdgcn_rsqf(var + EPS);
    const float lin = fmaf(rs, Di + Dj, Sew);
    // pass 2: nonlinear term
    const v4f* G4 = (const v4f*)&Gs[0];
    const v4f* E4 = (const v4f*)&Es[0];
    const v4f* W4 = (const v4f*)&Ws[0];
    const v2f rs2 = {rs, rs};
    const v2f two2 = {2.f, 2.f};
    v2f acc0 = {0.f, 0.f}, acc1 = {0.f, 0.f};
#pragma unroll 2
    for (int d8 = 0; d8 < 32; ++d8) {
        v4f xiA = *(const v4f*)(FIp + d8 * 8);
        v4f xiB = *(const v4f*)(FIp + d8 * 8 + 4);
        v4f gA = G4[d8 * 2], gB = G4[d8 * 2 + 1];
        v4f eA = E4[d8 * 2], eB = E4[d8 * 2 + 1];
        v4f wA = W4[d8 * 2], wB = W4[d8 * 2 + 1];
        MISH8(FJp + d8 * 8, rs2, acc0, acc1);
    }
    const float nl = (acc0.x + acc0.y) + (acc1.x + acc1.y);
    out[i * 768 + j] = fmaf(-2.f, nl, lin) + bc2f;
    if (write_mask) out[LOGITS_N + i * 768 + j] = 1.0f;
}

extern "C" void kernel_launch(void* const* d_in, const int* in_sizes, int n_in,
                              void* d_out, int out_size, void* d_ws, size_t ws_size,
                              hipStream_t stream) {
    const float* h   = (const float*)d_in[0];
    const float* W0  = (const float*)d_in[1];
    const float* b0  = (const float*)d_in[2];
    const float* g0  = (const float*)d_in[3];
    const float* be0 = (const float*)d_in[4];
    const float* W1  = (const float*)d_in[5];
    const float* b1  = (const float*)d_in[6];
    const float* Wc1 = (const float*)d_in[7];
    const float* bc1 = (const float*)d_in[8];
    const float* gc  = (const float*)d_in[9];
    const float* bec = (const float*)d_in[10];
    const float* Wc2 = (const float*)d_in[11];
    const float* bc2 = (const float*)d_in[12];
    float* ws = (float*)d_ws;
    float* fi     = ws;             // 768*256
    float* fjb    = ws + 196608;    // 768*256
    float* stats  = ws + 393216;    // 768*8
    float* Gp     = ws + 399360;    // 256
    float* Ep     = ws + 399616;    // 256
    float* Wp     = ws + 399872;    // 256
    float* consts = ws + 400128;    // 4
    float* out = (float*)d_out;
    int write_mask = (out_size >= 2 * LOGITS_N) ? 1 : 0;

    k1_rows<<<dim3(384), dim3(256), 0, stream>>>(h, W0, b0, g0, be0, W1, b1,
                                                 Wc1, bc1, gc, bec, Wc2,
                                                 fi, fjb, stats, Gp, Ep, Wp,
                                                 consts);
    k3_pair<<<dim3(48, 48), dim3(256), 0, stream>>>(fi, fjb, stats,
                                                    Gp, Ep, Wp, consts, bc2,
                                                    out, write_mask);
}